// Round 1
// baseline (1393.705 us; speedup 1.0000x reference)
//
#include <hip/hip_runtime.h>
#include <math.h>

#define B_ 4
#define CIN 64
#define H_ 160
#define W_ 160
#define COUT 64
#define KK_ 9
#define HW_ (H_ * W_)

// ---------------------------------------------------------------------------
// Kernel 1: transpose x (NCHW) -> x_nhwc  [b][h][w][c]
// tile: 64 channels x 32 w, LDS pitch 33 (bank-conflict-free both phases)
// ---------------------------------------------------------------------------
__global__ __launch_bounds__(256) void transpose_x_k(const float* __restrict__ x,
                                                     float* __restrict__ xt) {
    __shared__ float tile[64][33];
    int bid = blockIdx.x;             // b*H*5 + h*5 + wt
    int wt = bid % 5; int tmp = bid / 5;
    int h = tmp % H_; int b = tmp / H_;
    int wbase = wt * 32;
    int t = threadIdx.x;

    // read phase: lanes = 32 consecutive w, 8 channels per pass
    int w_r = t & 31, c_r = t >> 5;   // c_r in 0..7
    const float* xp = x + (size_t)b * CIN * HW_ + (size_t)h * W_ + wbase + w_r;
#pragma unroll
    for (int cl = 0; cl < 8; cl++) {
        int c = cl * 8 + c_r;
        tile[c][w_r] = xp[(size_t)c * HW_];
    }
    __syncthreads();

    // write phase: lanes = 64 consecutive channels -> 256B coalesced stores
    int c_w = t & 63, w_w = t >> 6;   // w_w in 0..3
    float* op = xt + ((size_t)(b * H_ + h) * W_ + wbase) * 64 + c_w;
#pragma unroll
    for (int wl = 0; wl < 8; wl++) {
        int w = wl * 4 + w_w;
        op[(size_t)w * 64] = tile[c_w][w];
    }
}

// ---------------------------------------------------------------------------
// Kernel 2: transpose weight (Cout, Cin, 3, 3) -> wT [k][c][o]  (o fastest)
// ---------------------------------------------------------------------------
__global__ void transpose_w_k(const float* __restrict__ w, float* __restrict__ wT) {
    int i = blockIdx.x * 256 + threadIdx.x;   // 9*64*64 = 36864 total
    if (i >= KK_ * CIN * COUT) return;
    int o = i & 63;
    int c = (i >> 6) & 63;
    int k = i >> 12;
    wT[i] = w[(o * CIN + c) * KK_ + k];
}

// ---------------------------------------------------------------------------
// Kernel 3: offset conv (3x3, pad 1) -> dy/dx/mask planes [b][k][h][w]
//   dy_k = out[2k], dx_k = out[2k+1], mask_k = sigmoid(out[18+k])
// ---------------------------------------------------------------------------
__global__ __launch_bounds__(256) void offset_conv_k(const float* __restrict__ x,
                                                     const float* __restrict__ ow,
                                                     const float* __restrict__ ob,
                                                     float* __restrict__ dy,
                                                     float* __restrict__ dx,
                                                     float* __restrict__ msk) {
    int i = blockIdx.x * 256 + threadIdx.x;   // B*27*H*W = 2,764,800
    int w = i % W_;
    int tmp = i / W_;
    int h = tmp % H_; tmp /= H_;
    int oc = tmp % 27;
    int b = tmp / 27;

    float acc = ob[oc];
    const float* xb = x + (size_t)b * CIN * HW_;
    const float* wp = ow + oc * CIN * 9;
    for (int c = 0; c < CIN; c++) {
        const float* xc = xb + (size_t)c * HW_;
        const float* wc = wp + c * 9;
#pragma unroll
        for (int ki = 0; ki < 3; ki++) {
            int y = h + ki - 1;
            if (y < 0 || y >= H_) continue;
#pragma unroll
            for (int kj = 0; kj < 3; kj++) {
                int xw = w + kj - 1;
                if (xw < 0 || xw >= W_) continue;
                acc += wc[ki * 3 + kj] * xc[y * W_ + xw];
            }
        }
    }
    int pix = h * W_ + w;
    if (oc < 18) {
        int k = oc >> 1;
        float* dst = (oc & 1) ? dx : dy;
        dst[(b * KK_ + k) * HW_ + pix] = acc;
    } else {
        msk[(b * KK_ + (oc - 18)) * HW_ + pix] = 1.f / (1.f + expf(-acc));
    }
}

// ---------------------------------------------------------------------------
// Kernel 4: deformable conv main.
// Block = 16 consecutive pixels (one row segment, one b), 256 threads.
// Gather phase: lanes = 64 channels (NHWC coalesced), stage modulated
//   bilinear samples in LDS val[p][k*64+c], pitch 577 (conflict-free).
// Compute phase: thread = (p in 0..15, og in 0..15), 4 outputs each via
//   float4 weight loads from wT (L1-broadcast), LDS val broadcast.
// ---------------------------------------------------------------------------
__global__ __launch_bounds__(256) void deform_main_k(const float* __restrict__ xt,
                                                     const float* __restrict__ dy_,
                                                     const float* __restrict__ dx_,
                                                     const float* __restrict__ msk_,
                                                     const float* __restrict__ wT,
                                                     const float* __restrict__ bias,
                                                     float* __restrict__ out) {
    __shared__ float sval[16 * 577];
    int t = threadIdx.x;
    int gp0 = blockIdx.x * 16;          // 16 | W, so one row / one b per block
    int wo0 = gp0 % W_;
    int tmp = gp0 / W_;
    int ho = tmp % H_;
    int b = tmp / H_;

    // ---- gather phase ----
    {
        int c = t & 63;
        int psub = t >> 6;              // wave id: each wave = 64 channels, 1 pixel
        const float* xb = xt + (size_t)b * HW_ * 64;
        for (int po = 0; po < 4; po++) {
            int p = po * 4 + psub;
            int wo = wo0 + p;
            int pixoff = (b * KK_) * HW_ + ho * W_ + wo;
#pragma unroll
            for (int k = 0; k < 9; k++) {
                float dyv = dy_[pixoff + k * HW_];
                float dxv = dx_[pixoff + k * HW_];
                float mv  = msk_[pixoff + k * HW_];
                float py = dyv + (float)(k / 3) + (float)(ho - 1);
                float px = dxv + (float)(k % 3) + (float)(wo - 1);
                float y0f = floorf(py), x0f = floorf(px);
                float wy1 = py - y0f, wx1 = px - x0f;
                float wy0 = 1.f - wy1, wx0 = 1.f - wx1;
                int y0 = (int)y0f, x0 = (int)x0f;
                bool yv0 = (y0 >= 0) && (y0 < H_);
                bool yv1 = (y0 + 1 >= 0) && (y0 + 1 < H_);
                bool xv0 = (x0 >= 0) && (x0 < W_);
                bool xv1 = (x0 + 1 >= 0) && (x0 + 1 < W_);
                float v = 0.f;
                if (yv0 && xv0) v += wy0 * wx0 * xb[(size_t)(y0 * W_ + x0) * 64 + c];
                if (yv0 && xv1) v += wy0 * wx1 * xb[(size_t)(y0 * W_ + x0 + 1) * 64 + c];
                if (yv1 && xv0) v += wy1 * wx0 * xb[(size_t)((y0 + 1) * W_ + x0) * 64 + c];
                if (yv1 && xv1) v += wy1 * wx1 * xb[(size_t)((y0 + 1) * W_ + x0 + 1) * 64 + c];
                sval[p * 577 + k * 64 + c] = v * mv;
            }
        }
    }
    __syncthreads();

    // ---- compute phase ----
    int p = t & 15;
    int og = t >> 4;                    // 0..15, 4 output channels each
    const float4* wT4 = (const float4*)wT;
    float4 acc;
    acc.x = bias[og * 4 + 0];
    acc.y = bias[og * 4 + 1];
    acc.z = bias[og * 4 + 2];
    acc.w = bias[og * 4 + 3];
    const float* sv = sval + p * 577;
#pragma unroll 3
    for (int k = 0; k < 9; k++) {
#pragma unroll 4
        for (int c2 = 0; c2 < 64; c2++) {
            float v = sv[k * 64 + c2];
            float4 w4 = wT4[(k * 64 + c2) * 16 + og];
            acc.x += v * w4.x;
            acc.y += v * w4.y;
            acc.z += v * w4.z;
            acc.w += v * w4.w;
        }
    }
    int wo = wo0 + p;
    float* op = out + ((size_t)(b * COUT + og * 4) * H_ + ho) * W_ + wo;
    op[0]            = acc.x;
    op[HW_]          = acc.y;
    op[2 * (size_t)HW_] = acc.z;
    op[3 * (size_t)HW_] = acc.w;
}

// ---------------------------------------------------------------------------
extern "C" void kernel_launch(void* const* d_in, const int* in_sizes, int n_in,
                              void* d_out, int out_size, void* d_ws, size_t ws_size,
                              hipStream_t stream) {
    const float* x    = (const float*)d_in[0];   // (4,64,160,160)
    const float* ow   = (const float*)d_in[1];   // (27,64,3,3)
    const float* ob   = (const float*)d_in[2];   // (27,)
    const float* wgt  = (const float*)d_in[3];   // (64,64,3,3)
    const float* bias = (const float*)d_in[4];   // (64,)
    float* out = (float*)d_out;                  // (4,64,160,160) fp32

    // workspace layout (floats): x_nhwc | dy | dx | mask | wT  = ~37.4 MB
    float* ws  = (float*)d_ws;
    float* xt  = ws;                         // 4*160*160*64 = 6,553,600
    float* dy  = xt + (size_t)B_ * HW_ * CIN;     // 4*9*25600 = 921,600
    float* dx  = dy + (size_t)B_ * KK_ * HW_;
    float* msk = dx + (size_t)B_ * KK_ * HW_;
    float* wT  = msk + (size_t)B_ * KK_ * HW_;    // 36,864

    transpose_x_k<<<B_ * H_ * 5, 256, 0, stream>>>(x, xt);
    transpose_w_k<<<(KK_ * CIN * COUT + 255) / 256, 256, 0, stream>>>(wgt, wT);
    offset_conv_k<<<(B_ * 27 * HW_) / 256, 256, 0, stream>>>(x, ow, ob, dy, dx, msk);
    deform_main_k<<<(B_ * HW_) / 16, 256, 0, stream>>>(xt, dy, dx, msk, wT, bias, out);
}

// Round 2
// 910.847 us; speedup vs baseline: 1.5301x; 1.5301x over previous
//
#include <hip/hip_runtime.h>
#include <math.h>

#define B_ 4
#define CIN 64
#define H_ 160
#define W_ 160
#define COUT 64
#define KK_ 9
#define HW_ (H_ * W_)

// ---------------------------------------------------------------------------
// Kernel 1: transpose x (NCHW) -> x_nhwc  [b][h][w][c]
// ---------------------------------------------------------------------------
__global__ __launch_bounds__(256) void transpose_x_k(const float* __restrict__ x,
                                                     float* __restrict__ xt) {
    __shared__ float tile[64][33];
    int bid = blockIdx.x;             // b*H*5 + h*5 + wt
    int wt = bid % 5; int tmp = bid / 5;
    int h = tmp % H_; int b = tmp / H_;
    int wbase = wt * 32;
    int t = threadIdx.x;

    int w_r = t & 31, c_r = t >> 5;   // c_r in 0..7
    const float* xp = x + (size_t)b * CIN * HW_ + (size_t)h * W_ + wbase + w_r;
#pragma unroll
    for (int cl = 0; cl < 8; cl++) {
        int c = cl * 8 + c_r;
        tile[c][w_r] = xp[(size_t)c * HW_];
    }
    __syncthreads();

    int c_w = t & 63, w_w = t >> 6;   // w_w in 0..3
    float* op = xt + ((size_t)(b * H_ + h) * W_ + wbase) * 64 + c_w;
#pragma unroll
    for (int wl = 0; wl < 8; wl++) {
        int w = wl * 4 + w_w;
        op[(size_t)w * 64] = tile[c_w][w];
    }
}

// ---------------------------------------------------------------------------
// Kernel 2: transpose main weight (Cout, Cin, 3, 3) -> wT [k][c][o] (o fastest)
// ---------------------------------------------------------------------------
__global__ void transpose_w_k(const float* __restrict__ w, float* __restrict__ wT) {
    int i = blockIdx.x * 256 + threadIdx.x;   // 9*64*64 = 36864
    if (i >= KK_ * CIN * COUT) return;
    int o = i & 63;
    int c = (i >> 6) & 63;
    int k = i >> 12;
    wT[i] = w[(o * CIN + c) * KK_ + k];
}

// ---------------------------------------------------------------------------
// Kernel 2b: transpose offset weight (27, 64, 3, 3) -> wt2 [c][k][oc] (oc fastest)
// ---------------------------------------------------------------------------
__global__ void transpose_ow_k(const float* __restrict__ w, float* __restrict__ wt2) {
    int i = blockIdx.x * 256 + threadIdx.x;   // 64*9*27 = 15552
    if (i >= CIN * KK_ * 27) return;
    int oc = i % 27;
    int k = (i / 27) % KK_;
    int c = i / (27 * KK_);
    wt2[i] = w[(oc * CIN + c) * KK_ + k];
}

// ---------------------------------------------------------------------------
// Kernel 3 v2: offset conv. Block = 64 pixels x 4 c-groups (16 ch each).
// Thread: 27 accumulators in VGPRs; weights via wave-uniform indices ->
// compiler scalarizes to s_load (SGPR FMA operand, no vmem-pipe cost).
// FMA:vector-load = 243:9 per channel. LDS reduce across the 4 c-groups.
// ---------------------------------------------------------------------------
__global__ __launch_bounds__(256) void offset_conv_k(const float* __restrict__ x,
                                                     const float* __restrict__ wt2,
                                                     const float* __restrict__ ob,
                                                     float* __restrict__ dy,
                                                     float* __restrict__ dx,
                                                     float* __restrict__ msk) {
    __shared__ float red[3][64][29];   // pitch 29 (odd) -> conflict-free
    int t = threadIdx.x;
    int pix = t & 63;
    int grp = t >> 6;                  // 0..3, channels grp*16 .. +15

    int gp = blockIdx.x * 64 + pix;    // 64 | HW, so one b per block
    int b = gp / HW_;
    int pixg = gp % HW_;
    int h = pixg / W_;
    int w = pixg % W_;

    float acc[27];
#pragma unroll
    for (int oc = 0; oc < 27; oc++) acc[oc] = 0.f;

    // boundary masks (per-lane, computed once)
    int ym1ok = (h - 1 >= 0), yp1ok = (h + 1 < H_);
    int xm1ok = (w - 1 >= 0), xp1ok = (w + 1 < W_);
    int c0 = grp * 16;
    const float* xb = x + ((size_t)b * CIN + c0) * HW_ + pixg;

    for (int cc = 0; cc < 16; cc++) {
        const float* xc = xb + (size_t)cc * HW_;
        float xv[9];
        xv[0] = (ym1ok && xm1ok) ? xc[-W_ - 1] : 0.f;
        xv[1] = (ym1ok)          ? xc[-W_]     : 0.f;
        xv[2] = (ym1ok && xp1ok) ? xc[-W_ + 1] : 0.f;
        xv[3] = (xm1ok)          ? xc[-1]      : 0.f;
        xv[4] =                    xc[0];
        xv[5] = (xp1ok)          ? xc[1]       : 0.f;
        xv[6] = (yp1ok && xm1ok) ? xc[W_ - 1]  : 0.f;
        xv[7] = (yp1ok)          ? xc[W_]      : 0.f;
        xv[8] = (yp1ok && xp1ok) ? xc[W_ + 1]  : 0.f;

        const float* wc = wt2 + (c0 + cc) * 243;   // [k][oc], wave-uniform
#pragma unroll
        for (int k = 0; k < 9; k++) {
            float xk = xv[k];
#pragma unroll
            for (int oc = 0; oc < 27; oc++) {
                acc[oc] += wc[k * 27 + oc] * xk;
            }
        }
    }

    if (grp > 0) {
#pragma unroll
        for (int oc = 0; oc < 27; oc++) red[grp - 1][pix][oc] = acc[oc];
    }
    __syncthreads();
    if (grp == 0) {
#pragma unroll
        for (int j = 0; j < 3; j++)
#pragma unroll
            for (int oc = 0; oc < 27; oc++) acc[oc] += red[j][pix][oc];

        // write dy/dx/mask planes [b][k][HW]; lanes = 64 consecutive pixels
        size_t base = (size_t)(b * KK_) * HW_ + pixg;
#pragma unroll
        for (int k = 0; k < 9; k++) {
            dy[base + (size_t)k * HW_] = acc[2 * k]     + ob[2 * k];
            dx[base + (size_t)k * HW_] = acc[2 * k + 1] + ob[2 * k + 1];
            float m = acc[18 + k] + ob[18 + k];
            msk[base + (size_t)k * HW_] = 1.f / (1.f + expf(-m));
        }
    }
}

// ---------------------------------------------------------------------------
// Kernel 4 v2: deformable conv main.
// Block = 32 consecutive pixels (one row segment), 256 threads.
// Gather: 4 waves x 8 pixels; lanes = 64 channels, NHWC coalesced bilinear.
//   LDS sval[p][k*64+c], pitch 580 (16B aligned, write conflict-free).
// Compute: thread = (p2 = 2 pixels, og = 4 out-channels); per (k,c-quad):
//   2x ds_read_b128 + 4x float4 weight loads + 32 FMAs -> VALU-bound.
// ---------------------------------------------------------------------------
__global__ __launch_bounds__(256) void deform_main_k(const float* __restrict__ xt,
                                                     const float* __restrict__ dy_,
                                                     const float* __restrict__ dx_,
                                                     const float* __restrict__ msk_,
                                                     const float* __restrict__ wT,
                                                     const float* __restrict__ bias,
                                                     float* __restrict__ out) {
    __shared__ float sval[32 * 580];
    int t = threadIdx.x;
    int gp0 = blockIdx.x * 32;          // 32 | W, one row / one b per block
    int wo0 = gp0 % W_;
    int tmp = gp0 / W_;
    int ho = tmp % H_;
    int b = tmp / H_;

    // ---- gather phase ----
    {
        int c = t & 63;
        int wv = t >> 6;                // wave id; wave handles pixels wv*8..+7
        const float* xb = xt + (size_t)b * HW_ * 64 + c;
        for (int j = 0; j < 8; j++) {
            int p = wv * 8 + j;
            int wo = wo0 + p;
            int pixoff = (b * KK_) * HW_ + ho * W_ + wo;
            float* sp = sval + p * 580;
#pragma unroll
            for (int k = 0; k < 9; k++) {
                float dyv = dy_[pixoff + k * HW_];
                float dxv = dx_[pixoff + k * HW_];
                float mv  = msk_[pixoff + k * HW_];
                float py = dyv + (float)(k / 3) + (float)(ho - 1);
                float px = dxv + (float)(k % 3) + (float)(wo - 1);
                float y0f = floorf(py), x0f = floorf(px);
                float wy1 = py - y0f, wx1 = px - x0f;
                float wy0 = 1.f - wy1, wx0 = 1.f - wx1;
                int y0 = (int)y0f, x0 = (int)x0f;
                bool yv0 = (y0 >= 0) && (y0 < H_);
                bool yv1 = (y0 + 1 >= 0) && (y0 + 1 < H_);
                bool xv0 = (x0 >= 0) && (x0 < W_);
                bool xv1 = (x0 + 1 >= 0) && (x0 + 1 < W_);
                float v = 0.f;
                if (yv0 && xv0) v += wy0 * wx0 * xb[(size_t)(y0 * W_ + x0) * 64];
                if (yv0 && xv1) v += wy0 * wx1 * xb[(size_t)(y0 * W_ + x0 + 1) * 64];
                if (yv1 && xv0) v += wy1 * wx0 * xb[(size_t)((y0 + 1) * W_ + x0) * 64];
                if (yv1 && xv1) v += wy1 * wx1 * xb[(size_t)((y0 + 1) * W_ + x0 + 1) * 64];
                sp[k * 64 + c] = v * mv;
            }
        }
    }
    __syncthreads();

    // ---- compute phase ----
    int p2 = t & 15;                    // pixels 2*p2, 2*p2+1
    int og = t >> 4;                    // 0..15, out-channels og*4..+3
    const float4* wT4 = (const float4*)wT;
    float4 b4 = ((const float4*)bias)[og];
    float4 acc0 = b4, acc1 = b4;
    const float* s0 = sval + (2 * p2) * 580;
    const float* s1 = s0 + 580;

#pragma unroll 3
    for (int k = 0; k < 9; k++) {
#pragma unroll 4
        for (int c4 = 0; c4 < 16; c4++) {
            int base = k * 64 + c4 * 4;
            float4 a0 = *(const float4*)(s0 + base);
            float4 a1 = *(const float4*)(s1 + base);
            float4 w0 = wT4[(base + 0) * 16 + og];
            float4 w1 = wT4[(base + 1) * 16 + og];
            float4 w2 = wT4[(base + 2) * 16 + og];
            float4 w3 = wT4[(base + 3) * 16 + og];
            acc0.x += a0.x * w0.x; acc0.y += a0.x * w0.y; acc0.z += a0.x * w0.z; acc0.w += a0.x * w0.w;
            acc1.x += a1.x * w0.x; acc1.y += a1.x * w0.y; acc1.z += a1.x * w0.z; acc1.w += a1.x * w0.w;
            acc0.x += a0.y * w1.x; acc0.y += a0.y * w1.y; acc0.z += a0.y * w1.z; acc0.w += a0.y * w1.w;
            acc1.x += a1.y * w1.x; acc1.y += a1.y * w1.y; acc1.z += a1.y * w1.z; acc1.w += a1.y * w1.w;
            acc0.x += a0.z * w2.x; acc0.y += a0.z * w2.y; acc0.z += a0.z * w2.z; acc0.w += a0.z * w2.w;
            acc1.x += a1.z * w2.x; acc1.y += a1.z * w2.y; acc1.z += a1.z * w2.z; acc1.w += a1.z * w2.w;
            acc0.x += a0.w * w3.x; acc0.y += a0.w * w3.y; acc0.z += a0.w * w3.z; acc0.w += a0.w * w3.w;
            acc1.x += a1.w * w3.x; acc1.y += a1.w * w3.y; acc1.z += a1.w * w3.z; acc1.w += a1.w * w3.w;
        }
    }

    float* op = out + ((size_t)(b * COUT + og * 4)) * HW_ + ho * W_ + wo0 + 2 * p2;
    op[0] = acc0.x; op[1] = acc1.x;
    op[HW_] = acc0.y; op[HW_ + 1] = acc1.y;
    op[2 * (size_t)HW_] = acc0.z; op[2 * (size_t)HW_ + 1] = acc1.z;
    op[3 * (size_t)HW_] = acc0.w; op[3 * (size_t)HW_ + 1] = acc1.w;
}

// ---------------------------------------------------------------------------
extern "C" void kernel_launch(void* const* d_in, const int* in_sizes, int n_in,
                              void* d_out, int out_size, void* d_ws, size_t ws_size,
                              hipStream_t stream) {
    const float* x    = (const float*)d_in[0];   // (4,64,160,160)
    const float* ow   = (const float*)d_in[1];   // (27,64,3,3)
    const float* ob   = (const float*)d_in[2];   // (27,)
    const float* wgt  = (const float*)d_in[3];   // (64,64,3,3)
    const float* bias = (const float*)d_in[4];   // (64,)
    float* out = (float*)d_out;                  // (4,64,160,160) fp32

    // workspace (floats): x_nhwc | dy | dx | mask | wT | wt2  = ~37.5 MB
    float* ws  = (float*)d_ws;
    float* xt  = ws;                                  // 6,553,600
    float* dy  = xt + (size_t)B_ * HW_ * CIN;         // 921,600 each
    float* dx  = dy + (size_t)B_ * KK_ * HW_;
    float* msk = dx + (size_t)B_ * KK_ * HW_;
    float* wT  = msk + (size_t)B_ * KK_ * HW_;        // 36,864
    float* wt2 = wT + (size_t)KK_ * CIN * COUT;       // 15,552

    transpose_x_k<<<B_ * H_ * 5, 256, 0, stream>>>(x, xt);
    transpose_w_k<<<(KK_ * CIN * COUT + 255) / 256, 256, 0, stream>>>(wgt, wT);
    transpose_ow_k<<<(CIN * KK_ * 27 + 255) / 256, 256, 0, stream>>>(ow, wt2);
    offset_conv_k<<<(B_ * HW_) / 64, 256, 0, stream>>>(x, wt2, ob, dy, dx, msk);
    deform_main_k<<<(B_ * HW_) / 32, 256, 0, stream>>>(xt, dy, dx, msk, wT, bias, out);
}

// Round 5
// 822.762 us; speedup vs baseline: 1.6939x; 1.1071x over previous
//
#include <hip/hip_runtime.h>
#include <math.h>

#define B_ 4
#define CIN 64
#define H_ 160
#define W_ 160
#define COUT 64
#define KK_ 9
#define HW_ (H_ * W_)

// ---------------------------------------------------------------------------
// Kernel 1: transpose x (NCHW fp32) -> xt NHWC fp32  [b][h][w][c]  (R2-exact)
// ---------------------------------------------------------------------------
__global__ __launch_bounds__(256) void transpose_x_k(const float* __restrict__ x,
                                                     float* __restrict__ xt) {
    __shared__ float tile[64][33];
    int bid = blockIdx.x;             // b*H*5 + h*5 + wt
    int wt = bid % 5; int tmp = bid / 5;
    int h = tmp % H_; int b = tmp / H_;
    int wbase = wt * 32;
    int t = threadIdx.x;

    int w_r = t & 31, c_r = t >> 5;
    const float* xp = x + (size_t)b * CIN * HW_ + (size_t)h * W_ + wbase + w_r;
#pragma unroll
    for (int cl = 0; cl < 8; cl++) {
        int c = cl * 8 + c_r;
        tile[c][w_r] = xp[(size_t)c * HW_];
    }
    __syncthreads();

    int c_w = t & 63, w_w = t >> 6;
    float* op = xt + ((size_t)(b * H_ + h) * W_ + wbase) * 64 + c_w;
#pragma unroll
    for (int wl = 0; wl < 8; wl++) {
        int w = wl * 4 + w_w;
        op[(size_t)w * 64] = tile[c_w][w];
    }
}

// ---------------------------------------------------------------------------
// Kernel 2: transpose main weight (Cout,Cin,3,3) -> wT [k*64+c][o] (R2-exact)
// ---------------------------------------------------------------------------
__global__ void transpose_w_k(const float* __restrict__ w, float* __restrict__ wT) {
    int i = blockIdx.x * 256 + threadIdx.x;   // 9*64*64 = 36864
    if (i >= KK_ * CIN * COUT) return;
    int o = i & 63;
    int c = (i >> 6) & 63;
    int k = i >> 12;
    wT[i] = w[(o * CIN + c) * KK_ + k];
}

// ---------------------------------------------------------------------------
// Kernel 2b: transpose offset weight (27,64,3,3) -> wt2 [c][k][oc] (R2-exact)
// ---------------------------------------------------------------------------
__global__ void transpose_ow_k(const float* __restrict__ w, float* __restrict__ wt2) {
    int i = blockIdx.x * 256 + threadIdx.x;   // 64*9*27 = 15552
    if (i >= CIN * KK_ * 27) return;
    int oc = i % 27;
    int k = (i / 27) % KK_;
    int c = i / (27 * KK_);
    wt2[i] = w[(oc * CIN + c) * KK_ + k];
}

// ---------------------------------------------------------------------------
// Kernel 3: offset conv, fp32 (R2-exact arithmetic — PASSED in R2).
// Block = 64 pixels x 4 c-groups; scalar (SGPR) weight loads.
// ---------------------------------------------------------------------------
__global__ __launch_bounds__(256) void offset_conv_k(const float* __restrict__ x,
                                                     const float* __restrict__ wt2,
                                                     const float* __restrict__ ob,
                                                     float* __restrict__ dy,
                                                     float* __restrict__ dx,
                                                     float* __restrict__ msk) {
    __shared__ float red[3][64][29];   // pitch 29 (odd) -> conflict-free
    int t = threadIdx.x;
    int pix = t & 63;
    int grp = t >> 6;                  // 0..3, channels grp*16 .. +15

    int gp = blockIdx.x * 64 + pix;    // 64 | HW, so one b per block
    int b = gp / HW_;
    int pixg = gp % HW_;
    int h = pixg / W_;
    int w = pixg % W_;

    float acc[27];
#pragma unroll
    for (int oc = 0; oc < 27; oc++) acc[oc] = 0.f;

    int ym1ok = (h - 1 >= 0), yp1ok = (h + 1 < H_);
    int xm1ok = (w - 1 >= 0), xp1ok = (w + 1 < W_);
    int c0 = __builtin_amdgcn_readfirstlane(grp * 16);   // wave-uniform
    const float* xb = x + ((size_t)b * CIN + c0) * HW_ + pixg;

    for (int cc = 0; cc < 16; cc++) {
        const float* xc = xb + (size_t)cc * HW_;
        float xv[9];
        xv[0] = (ym1ok && xm1ok) ? xc[-W_ - 1] : 0.f;
        xv[1] = (ym1ok)          ? xc[-W_]     : 0.f;
        xv[2] = (ym1ok && xp1ok) ? xc[-W_ + 1] : 0.f;
        xv[3] = (xm1ok)          ? xc[-1]      : 0.f;
        xv[4] =                    xc[0];
        xv[5] = (xp1ok)          ? xc[1]       : 0.f;
        xv[6] = (yp1ok && xm1ok) ? xc[W_ - 1]  : 0.f;
        xv[7] = (yp1ok)          ? xc[W_]      : 0.f;
        xv[8] = (yp1ok && xp1ok) ? xc[W_ + 1]  : 0.f;

        const float* wc = wt2 + (c0 + cc) * 243;   // scalar pointer -> s_load
#pragma unroll
        for (int k = 0; k < 9; k++) {
            float xk = xv[k];
#pragma unroll
            for (int oc = 0; oc < 27; oc++) {
                acc[oc] += wc[k * 27 + oc] * xk;
            }
        }
    }

    if (grp > 0) {
#pragma unroll
        for (int oc = 0; oc < 27; oc++) red[grp - 1][pix][oc] = acc[oc];
    }
    __syncthreads();
    if (grp == 0) {
#pragma unroll
        for (int j = 0; j < 3; j++)
#pragma unroll
            for (int oc = 0; oc < 27; oc++) acc[oc] += red[j][pix][oc];

        size_t base = (size_t)(b * KK_) * HW_ + pixg;
#pragma unroll
        for (int k = 0; k < 9; k++) {
            dy[base + (size_t)k * HW_] = acc[2 * k]     + ob[2 * k];
            dx[base + (size_t)k * HW_] = acc[2 * k + 1] + ob[2 * k + 1];
            float m = acc[18 + k] + ob[18 + k];
            msk[base + (size_t)k * HW_] = 1.f / (1.f + expf(-m));
        }
    }
}

// ---------------------------------------------------------------------------
// Kernel 4: deformable conv, fp32 VALU (R2-exact gather; compute phase is
// R2 with the og/p2 thread-bit SWAP: og = t&15 makes sval reads wave-
// broadcast (conflict-free) and weight float4 loads lane-consecutive.
// ---------------------------------------------------------------------------
__global__ __launch_bounds__(256) void deform_main_k(const float* __restrict__ xt,
                                                     const float* __restrict__ dy_,
                                                     const float* __restrict__ dx_,
                                                     const float* __restrict__ msk_,
                                                     const float* __restrict__ wT,
                                                     const float* __restrict__ bias,
                                                     float* __restrict__ out) {
    __shared__ float sval[32 * 580];
    int t = threadIdx.x;
    int gp0 = blockIdx.x * 32;          // 32 | W, one row / one b per block
    int wo0 = gp0 % W_;
    int tmp = gp0 / W_;
    int ho = tmp % H_;
    int b = tmp / H_;

    // ---- gather phase (R2 verbatim) ----
    {
        int c = t & 63;
        int wv = t >> 6;                // wave handles pixels wv*8..+7
        const float* xb = xt + (size_t)b * HW_ * 64 + c;
        for (int j = 0; j < 8; j++) {
            int p = wv * 8 + j;
            int wo = wo0 + p;
            int pixoff = (b * KK_) * HW_ + ho * W_ + wo;
            float* sp = sval + p * 580;
#pragma unroll
            for (int k = 0; k < 9; k++) {
                float dyv = dy_[pixoff + k * HW_];
                float dxv = dx_[pixoff + k * HW_];
                float mv  = msk_[pixoff + k * HW_];
                float py = dyv + (float)(k / 3) + (float)(ho - 1);
                float px = dxv + (float)(k % 3) + (float)(wo - 1);
                float y0f = floorf(py), x0f = floorf(px);
                float wy1 = py - y0f, wx1 = px - x0f;
                float wy0 = 1.f - wy1, wx0 = 1.f - wx1;
                int y0 = (int)y0f, x0 = (int)x0f;
                bool yv0 = (y0 >= 0) && (y0 < H_);
                bool yv1 = (y0 + 1 >= 0) && (y0 + 1 < H_);
                bool xv0 = (x0 >= 0) && (x0 < W_);
                bool xv1 = (x0 + 1 >= 0) && (x0 + 1 < W_);
                float v = 0.f;
                if (yv0 && xv0) v += wy0 * wx0 * xb[(size_t)(y0 * W_ + x0) * 64];
                if (yv0 && xv1) v += wy0 * wx1 * xb[(size_t)(y0 * W_ + x0 + 1) * 64];
                if (yv1 && xv0) v += wy1 * wx0 * xb[(size_t)((y0 + 1) * W_ + x0) * 64];
                if (yv1 && xv1) v += wy1 * wx1 * xb[(size_t)((y0 + 1) * W_ + x0 + 1) * 64];
                sp[k * 64 + c] = v * mv;
            }
        }
    }
    __syncthreads();

    // ---- compute phase (R2 math, og/p2 bit-swapped) ----
    int og = t & 15;                    // out-channels og*4..+3  (lane-fast)
    int p2 = t >> 4;                    // pixels 2*p2, 2*p2+1
    const float4* wT4 = (const float4*)wT;
    float4 b4 = ((const float4*)bias)[og];
    float4 acc0 = b4, acc1 = b4;
    const float* s0 = sval + (2 * p2) * 580;
    const float* s1 = s0 + 580;

#pragma unroll 3
    for (int k = 0; k < 9; k++) {
#pragma unroll 4
        for (int c4 = 0; c4 < 16; c4++) {
            int base = k * 64 + c4 * 4;
            float4 a0 = *(const float4*)(s0 + base);
            float4 a1 = *(const float4*)(s1 + base);
            float4 w0 = wT4[(base + 0) * 16 + og];
            float4 w1 = wT4[(base + 1) * 16 + og];
            float4 w2 = wT4[(base + 2) * 16 + og];
            float4 w3 = wT4[(base + 3) * 16 + og];
            acc0.x += a0.x * w0.x; acc0.y += a0.x * w0.y; acc0.z += a0.x * w0.z; acc0.w += a0.x * w0.w;
            acc1.x += a1.x * w0.x; acc1.y += a1.x * w0.y; acc1.z += a1.x * w0.z; acc1.w += a1.x * w0.w;
            acc0.x += a0.y * w1.x; acc0.y += a0.y * w1.y; acc0.z += a0.y * w1.z; acc0.w += a0.y * w1.w;
            acc1.x += a1.y * w1.x; acc1.y += a1.y * w1.y; acc1.z += a1.y * w1.z; acc1.w += a1.y * w1.w;
            acc0.x += a0.z * w2.x; acc0.y += a0.z * w2.y; acc0.z += a0.z * w2.z; acc0.w += a0.z * w2.w;
            acc1.x += a1.z * w2.x; acc1.y += a1.z * w2.y; acc1.z += a1.z * w2.z; acc1.w += a1.z * w2.w;
            acc0.x += a0.w * w3.x; acc0.y += a0.w * w3.y; acc0.z += a0.w * w3.z; acc0.w += a0.w * w3.w;
            acc1.x += a1.w * w3.x; acc1.y += a1.w * w3.y; acc1.z += a1.w * w3.z; acc1.w += a1.w * w3.w;
        }
    }

    float* op = out + ((size_t)(b * COUT + og * 4)) * HW_ + ho * W_ + wo0 + 2 * p2;
    op[0] = acc0.x; op[1] = acc1.x;
    op[HW_] = acc0.y; op[HW_ + 1] = acc1.y;
    op[2 * (size_t)HW_] = acc0.z; op[2 * (size_t)HW_ + 1] = acc1.z;
    op[3 * (size_t)HW_] = acc0.w; op[3 * (size_t)HW_ + 1] = acc1.w;
}

// ---------------------------------------------------------------------------
extern "C" void kernel_launch(void* const* d_in, const int* in_sizes, int n_in,
                              void* d_out, int out_size, void* d_ws, size_t ws_size,
                              hipStream_t stream) {
    const float* x    = (const float*)d_in[0];   // (4,64,160,160)
    const float* ow   = (const float*)d_in[1];   // (27,64,3,3)
    const float* ob   = (const float*)d_in[2];   // (27,)
    const float* wgt  = (const float*)d_in[3];   // (64,64,3,3)
    const float* bias = (const float*)d_in[4];   // (64,)
    float* out = (float*)d_out;                  // (4,64,160,160) fp32

    // workspace (floats): x_nhwc | dy | dx | mask | wT | wt2  (~37.5 MB)
    float* ws  = (float*)d_ws;
    float* xt  = ws;                                  // 6,553,600
    float* dy  = xt + (size_t)B_ * HW_ * CIN;         // 921,600 each
    float* dx  = dy + (size_t)B_ * KK_ * HW_;
    float* msk = dx + (size_t)B_ * KK_ * HW_;
    float* wT  = msk + (size_t)B_ * KK_ * HW_;        // 36,864
    float* wt2 = wT + (size_t)KK_ * CIN * COUT;       // 15,552

    transpose_x_k<<<B_ * H_ * 5, 256, 0, stream>>>(x, xt);
    transpose_w_k<<<(KK_ * CIN * COUT + 255) / 256, 256, 0, stream>>>(wgt, wT);
    transpose_ow_k<<<(CIN * KK_ * 27 + 255) / 256, 256, 0, stream>>>(ow, wt2);
    offset_conv_k<<<(B_ * HW_) / 64, 256, 0, stream>>>(x, wt2, ob, dy, dx, msk);
    deform_main_k<<<(B_ * HW_) / 32, 256, 0, stream>>>(xt, dy, dx, msk, wT, bias, out);
}

// Round 6
// 600.503 us; speedup vs baseline: 2.3209x; 1.3701x over previous
//
#include <hip/hip_runtime.h>
#include <math.h>

#define B_ 4
#define CIN 64
#define H_ 160
#define W_ 160
#define COUT 64
#define KK_ 9
#define HW_ (H_ * W_)
#define KTOT 576      // 9 taps * 64 channels
#define APITCH 584    // bf16 LDS pitch: 1168 B = 73*16 (odd*16 -> b128 conflict-free)
#define CPITCH 196    // fp32 chunk pitch (3 taps * 64 + 4)

typedef __attribute__((ext_vector_type(8))) short bf16x8;
typedef __attribute__((ext_vector_type(4))) float f32x4;

__device__ inline unsigned short f2bf(float f) {
    unsigned int u = __float_as_uint(f);
    u = (u + 0x7FFF + ((u >> 16) & 1)) >> 16;   // round-to-nearest-even
    return (unsigned short)u;
}

// ---------------------------------------------------------------------------
// Kernel 1: transpose x (NCHW fp32) -> xt NHWC fp32  [b][h][w][c]  (R2-exact)
// ---------------------------------------------------------------------------
__global__ __launch_bounds__(256) void transpose_x_k(const float* __restrict__ x,
                                                     float* __restrict__ xt) {
    __shared__ float tile[64][33];
    int bid = blockIdx.x;             // b*H*5 + h*5 + wt
    int wt = bid % 5; int tmp = bid / 5;
    int h = tmp % H_; int b = tmp / H_;
    int wbase = wt * 32;
    int t = threadIdx.x;

    int w_r = t & 31, c_r = t >> 5;
    const float* xp = x + (size_t)b * CIN * HW_ + (size_t)h * W_ + wbase + w_r;
#pragma unroll
    for (int cl = 0; cl < 8; cl++) {
        int c = cl * 8 + c_r;
        tile[c][w_r] = xp[(size_t)c * HW_];
    }
    __syncthreads();

    int c_w = t & 63, w_w = t >> 6;
    float* op = xt + ((size_t)(b * H_ + h) * W_ + wbase) * 64 + c_w;
#pragma unroll
    for (int wl = 0; wl < 8; wl++) {
        int w = wl * 4 + w_w;
        op[(size_t)w * 64] = tile[c_w][w];
    }
}

// ---------------------------------------------------------------------------
// Kernel 2: transpose main weight (Cout,Cin,3,3) -> wT [k*64+c][o] (R2-exact)
// ---------------------------------------------------------------------------
__global__ void transpose_w_k(const float* __restrict__ w, float* __restrict__ wT) {
    int i = blockIdx.x * 256 + threadIdx.x;   // 9*64*64 = 36864
    if (i >= KK_ * CIN * COUT) return;
    int o = i & 63;
    int c = (i >> 6) & 63;
    int k = i >> 12;
    wT[i] = w[(o * CIN + c) * KK_ + k];
}

// ---------------------------------------------------------------------------
// Kernel 2b: offset weight (27,64,3,3) fp32 -> wB2 bf16 [n(32,pad0)][tap*64+c]
// ---------------------------------------------------------------------------
__global__ void prep_wB2_k(const float* __restrict__ w, unsigned short* __restrict__ wB2) {
    int i = blockIdx.x * 256 + threadIdx.x;     // 32*576
    if (i >= 32 * KTOT) return;
    int n = i / KTOT, r = i % KTOT;
    int tap = r >> 6, c = r & 63;
    wB2[i] = (n < 27) ? f2bf(w[(n * CIN + c) * KK_ + tap]) : (unsigned short)0;
}

// ---------------------------------------------------------------------------
// Kernel 3: offset conv via MFMA (the MFMA-mechanics experiment).
// Block = 32 pixels.  im2col -> LDS bf16 A[32][576]; 4 waves each compute one
// 16(pixels)x16(oc) tile, K=576; DIRECT stores from D layout (no LDS epilogue):
//   D col = lane&15 = oc, D row = (lane>>4)*4 + reg = pixel-in-mtile.
// ---------------------------------------------------------------------------
__global__ __launch_bounds__(256) void offset_mfma_k(const float* __restrict__ xt,
                                                     const unsigned short* __restrict__ wB2,
                                                     const float* __restrict__ ob,
                                                     float* __restrict__ dy,
                                                     float* __restrict__ dx,
                                                     float* __restrict__ msk) {
    __shared__ __align__(16) unsigned short sA[32 * APITCH];
    int t = threadIdx.x;
    int lane = t & 63, wv = t >> 6;
    int gp0 = blockIdx.x * 32;          // 32 | W: one row, one b per block
    int wo0 = gp0 % W_;
    int tmp = gp0 / W_;
    int ho = tmp % H_;
    int b  = tmp / H_;

    // ---- im2col gather (zero-pad borders), lanes = 64 channels ----
    {
        const float* xb = xt + (size_t)b * HW_ * 64 + lane;
        for (int i = 0; i < 72; i++) {
            int task = i * 4 + wv;      // 0..287 = k*32 + p
            int p = task & 31, k = task >> 5;
            int y  = ho + (k / 3) - 1;
            int xw = wo0 + p + (k % 3) - 1;
            float v = 0.f;
            if (y >= 0 && y < H_ && xw >= 0 && xw < W_)
                v = xb[(size_t)(y * W_ + xw) * 64];
            sA[p * APITCH + k * 64 + lane] = f2bf(v);
        }
    }
    __syncthreads();

    // ---- GEMM: wave wv -> (mtile = wv&1 pixels, ntile = wv>>1 channels) ----
    int mtile = wv & 1, ntile = wv >> 1;
    int m = lane & 15, q = lane >> 4;
    int oc = ntile * 16 + m;            // B col (= D col, lane&15-consistent)
    float bv = (oc < 27) ? ob[oc] : 0.f;
    f32x4 acc = {bv, bv, bv, bv};
    const unsigned short* arow = sA + (mtile * 16 + m) * APITCH + q * 8;
    const unsigned short* brow = wB2 + oc * KTOT + q * 8;
#pragma unroll
    for (int kk = 0; kk < 18; kk++) {
        bf16x8 af = *(const bf16x8*)(arow + kk * 32);
        bf16x8 bf = *(const bf16x8*)(brow + kk * 32);
        acc = __builtin_amdgcn_mfma_f32_16x16x32_bf16(af, bf, acc, 0, 0, 0);
    }

    // ---- direct store: 4 consecutive pixels (reg) x 1 channel per lane ----
    if (oc < 27) {
        int pbase = mtile * 16 + q * 4;           // pixel = pbase + reg
        if (oc < 18) {
            int k = oc >> 1;
            float* dst = (oc & 1) ? dx : dy;
            size_t addr = (size_t)(b * KK_ + k) * HW_ + (size_t)ho * W_ + wo0 + pbase;
            float4 r; r.x = acc[0]; r.y = acc[1]; r.z = acc[2]; r.w = acc[3];
            *(float4*)(dst + addr) = r;
        } else {
            int k = oc - 18;
            size_t addr = (size_t)(b * KK_ + k) * HW_ + (size_t)ho * W_ + wo0 + pbase;
            float4 r;
            r.x = 1.f / (1.f + expf(-acc[0]));
            r.y = 1.f / (1.f + expf(-acc[1]));
            r.z = 1.f / (1.f + expf(-acc[2]));
            r.w = 1.f / (1.f + expf(-acc[3]));
            *(float4*)(msk + addr) = r;
        }
    }
}

// ---------------------------------------------------------------------------
// Kernel 4: deformable conv, fp32 VALU (R5-exact arithmetic), K-CHUNKED:
// 3 taps per chunk -> LDS 25 KB -> ~5 blocks/CU (vs 2).  Gather chunk ->
// sync -> accumulate 192 K -> sync -> next.  Acc lives in registers.
// ---------------------------------------------------------------------------
__global__ __launch_bounds__(256, 5) void deform_main_k(const float* __restrict__ xt,
                                                        const float* __restrict__ dy_,
                                                        const float* __restrict__ dx_,
                                                        const float* __restrict__ msk_,
                                                        const float* __restrict__ wT,
                                                        const float* __restrict__ bias,
                                                        float* __restrict__ out) {
    __shared__ float sval[32 * CPITCH];
    int t = threadIdx.x;
    int gp0 = blockIdx.x * 32;          // 32 | W, one row / one b per block
    int wo0 = gp0 % W_;
    int tmp = gp0 / W_;
    int ho = tmp % H_;
    int b = tmp / H_;

    int c = t & 63, wv = t >> 6;        // gather mapping
    int og = t & 15, p2 = t >> 4;       // compute mapping
    const float* xb = xt + (size_t)b * HW_ * 64 + c;
    const float4* wT4 = (const float4*)wT;
    float4 b4 = ((const float4*)bias)[og];
    float4 acc0 = b4, acc1 = b4;
    const float* s0 = sval + (2 * p2) * CPITCH;
    const float* s1 = s0 + CPITCH;

    for (int chk = 0; chk < 3; chk++) {
        // ---- gather taps chk*3 .. chk*3+2 (R5-exact arithmetic) ----
        for (int j = 0; j < 8; j++) {
            int p = wv * 8 + j;
            int wo = wo0 + p;
            int pixoff = (b * KK_) * HW_ + ho * W_ + wo;
            float* sp = sval + p * CPITCH;
#pragma unroll
            for (int kt = 0; kt < 3; kt++) {
                int k = chk * 3 + kt;
                float dyv = dy_[pixoff + k * HW_];
                float dxv = dx_[pixoff + k * HW_];
                float mv  = msk_[pixoff + k * HW_];
                float py = dyv + (float)(k / 3) + (float)(ho - 1);
                float px = dxv + (float)(k % 3) + (float)(wo - 1);
                float y0f = floorf(py), x0f = floorf(px);
                float wy1 = py - y0f, wx1 = px - x0f;
                float wy0 = 1.f - wy1, wx0 = 1.f - wx1;
                int y0 = (int)y0f, x0 = (int)x0f;
                bool yv0 = (y0 >= 0) && (y0 < H_);
                bool yv1 = (y0 + 1 >= 0) && (y0 + 1 < H_);
                bool xv0 = (x0 >= 0) && (x0 < W_);
                bool xv1 = (x0 + 1 >= 0) && (x0 + 1 < W_);
                float v = 0.f;
                if (yv0 && xv0) v += wy0 * wx0 * xb[(size_t)(y0 * W_ + x0) * 64];
                if (yv0 && xv1) v += wy0 * wx1 * xb[(size_t)(y0 * W_ + x0 + 1) * 64];
                if (yv1 && xv0) v += wy1 * wx0 * xb[(size_t)((y0 + 1) * W_ + x0) * 64];
                if (yv1 && xv1) v += wy1 * wx1 * xb[(size_t)((y0 + 1) * W_ + x0 + 1) * 64];
                sp[kt * 64 + c] = v * mv;
            }
        }
        __syncthreads();

        // ---- accumulate this chunk's 192 K ----
#pragma unroll
        for (int kt = 0; kt < 3; kt++) {
#pragma unroll
            for (int c4 = 0; c4 < 16; c4++) {
                int base  = kt * 64 + c4 * 4;
                int wbase = (chk * 3 + kt) * 64 + c4 * 4;
                float4 a0 = *(const float4*)(s0 + base);
                float4 a1 = *(const float4*)(s1 + base);
                float4 w0 = wT4[(wbase + 0) * 16 + og];
                float4 w1 = wT4[(wbase + 1) * 16 + og];
                float4 w2 = wT4[(wbase + 2) * 16 + og];
                float4 w3 = wT4[(wbase + 3) * 16 + og];
                acc0.x += a0.x * w0.x; acc0.y += a0.x * w0.y; acc0.z += a0.x * w0.z; acc0.w += a0.x * w0.w;
                acc1.x += a1.x * w0.x; acc1.y += a1.x * w0.y; acc1.z += a1.x * w0.z; acc1.w += a1.x * w0.w;
                acc0.x += a0.y * w1.x; acc0.y += a0.y * w1.y; acc0.z += a0.y * w1.z; acc0.w += a0.y * w1.w;
                acc1.x += a1.y * w1.x; acc1.y += a1.y * w1.y; acc1.z += a1.y * w1.z; acc1.w += a1.y * w1.w;
                acc0.x += a0.z * w2.x; acc0.y += a0.z * w2.y; acc0.z += a0.z * w2.z; acc0.w += a0.z * w2.w;
                acc1.x += a1.z * w2.x; acc1.y += a1.z * w2.y; acc1.z += a1.z * w2.z; acc1.w += a1.z * w2.w;
                acc0.x += a0.w * w3.x; acc0.y += a0.w * w3.y; acc0.z += a0.w * w3.z; acc0.w += a0.w * w3.w;
                acc1.x += a1.w * w3.x; acc1.y += a1.w * w3.y; acc1.z += a1.w * w3.z; acc1.w += a1.w * w3.w;
            }
        }
        __syncthreads();
    }

    float* op = out + ((size_t)(b * COUT + og * 4)) * HW_ + ho * W_ + wo0 + 2 * p2;
    op[0] = acc0.x; op[1] = acc1.x;
    op[HW_] = acc0.y; op[HW_ + 1] = acc1.y;
    op[2 * (size_t)HW_] = acc0.z; op[2 * (size_t)HW_ + 1] = acc1.z;
    op[3 * (size_t)HW_] = acc0.w; op[3 * (size_t)HW_ + 1] = acc1.w;
}

// ---------------------------------------------------------------------------
extern "C" void kernel_launch(void* const* d_in, const int* in_sizes, int n_in,
                              void* d_out, int out_size, void* d_ws, size_t ws_size,
                              hipStream_t stream) {
    const float* x    = (const float*)d_in[0];   // (4,64,160,160)
    const float* ow   = (const float*)d_in[1];   // (27,64,3,3)
    const float* ob   = (const float*)d_in[2];   // (27,)
    const float* wgt  = (const float*)d_in[3];   // (64,64,3,3)
    const float* bias = (const float*)d_in[4];   // (64,)
    float* out = (float*)d_out;                  // (4,64,160,160) fp32

    // workspace (floats): x_nhwc | dy | dx | mask | wT | wB2(bf16)  (~37.5 MB)
    float* ws  = (float*)d_ws;
    float* xt  = ws;                                  // 6,553,600
    float* dy  = xt + (size_t)B_ * HW_ * CIN;         // 921,600 each
    float* dx  = dy + (size_t)B_ * KK_ * HW_;
    float* msk = dx + (size_t)B_ * KK_ * HW_;
    float* wT  = msk + (size_t)B_ * KK_ * HW_;        // 36,864 f32
    unsigned short* wB2 = (unsigned short*)(wT + (size_t)KK_ * CIN * COUT);  // 18,432 u16

    transpose_x_k<<<B_ * H_ * 5, 256, 0, stream>>>(x, xt);
    transpose_w_k<<<(KK_ * CIN * COUT + 255) / 256, 256, 0, stream>>>(wgt, wT);
    prep_wB2_k<<<(32 * KTOT + 255) / 256, 256, 0, stream>>>(ow, wB2);
    offset_mfma_k<<<(B_ * HW_) / 32, 256, 0, stream>>>(xt, wB2, ob, dy, dx, msk);
    deform_main_k<<<(B_ * HW_) / 32, 256, 0, stream>>>(xt, dy, dx, msk, wT, bias, out);
}

// Round 7
// 543.423 us; speedup vs baseline: 2.5647x; 1.1050x over previous
//
#include <hip/hip_runtime.h>
#include <math.h>

#define B_ 4
#define CIN 64
#define H_ 160
#define W_ 160
#define COUT 64
#define KK_ 9
#define HW_ (H_ * W_)
#define KTOT 576      // 9 taps * 64 channels
#define APITCH 584    // bf16 LDS pitch: 1168 B = 73*16 (odd*16 -> b128 conflict-free)

typedef __attribute__((ext_vector_type(8))) short bf16x8;
typedef __attribute__((ext_vector_type(4))) float f32x4;

__device__ inline unsigned short f2bf(float f) {
    unsigned int u = __float_as_uint(f);
    u = (u + 0x7FFF + ((u >> 16) & 1)) >> 16;   // round-to-nearest-even
    return (unsigned short)u;
}

// ---------------------------------------------------------------------------
// Kernel 1: transpose x (NCHW fp32) -> xt NHWC fp32  [b][h][w][c]  (verified)
// ---------------------------------------------------------------------------
__global__ __launch_bounds__(256) void transpose_x_k(const float* __restrict__ x,
                                                     float* __restrict__ xt) {
    __shared__ float tile[64][33];
    int bid = blockIdx.x;             // b*H*5 + h*5 + wt
    int wt = bid % 5; int tmp = bid / 5;
    int h = tmp % H_; int b = tmp / H_;
    int wbase = wt * 32;
    int t = threadIdx.x;

    int w_r = t & 31, c_r = t >> 5;
    const float* xp = x + (size_t)b * CIN * HW_ + (size_t)h * W_ + wbase + w_r;
#pragma unroll
    for (int cl = 0; cl < 8; cl++) {
        int c = cl * 8 + c_r;
        tile[c][w_r] = xp[(size_t)c * HW_];
    }
    __syncthreads();

    int c_w = t & 63, w_w = t >> 6;
    float* op = xt + ((size_t)(b * H_ + h) * W_ + wbase) * 64 + c_w;
#pragma unroll
    for (int wl = 0; wl < 8; wl++) {
        int w = wl * 4 + w_w;
        op[(size_t)w * 64] = tile[c_w][w];
    }
}

// ---------------------------------------------------------------------------
// Kernel 2: main weight (Cout,Cin,3,3) fp32 -> wB bf16 [o][tap*64+c]
// ---------------------------------------------------------------------------
__global__ void prep_wB_k(const float* __restrict__ w, unsigned short* __restrict__ wB) {
    int i = blockIdx.x * 256 + threadIdx.x;     // 64*576
    if (i >= COUT * KTOT) return;
    int o = i / KTOT, r = i % KTOT;
    int tap = r >> 6, c = r & 63;
    wB[i] = f2bf(w[(o * CIN + c) * KK_ + tap]);
}

// ---------------------------------------------------------------------------
// Kernel 2b: offset weight (27,64,3,3) fp32 -> wB2 bf16 [n(32,pad0)][tap*64+c]
// ---------------------------------------------------------------------------
__global__ void prep_wB2_k(const float* __restrict__ w, unsigned short* __restrict__ wB2) {
    int i = blockIdx.x * 256 + threadIdx.x;     // 32*576
    if (i >= 32 * KTOT) return;
    int n = i / KTOT, r = i % KTOT;
    int tap = r >> 6, c = r & 63;
    wB2[i] = (n < 27) ? f2bf(w[(n * CIN + c) * KK_ + tap]) : (unsigned short)0;
}

// ---------------------------------------------------------------------------
// Kernel 3: offset conv via MFMA (R6-verified PASSING kernel, unchanged).
// ---------------------------------------------------------------------------
__global__ __launch_bounds__(256) void offset_mfma_k(const float* __restrict__ xt,
                                                     const unsigned short* __restrict__ wB2,
                                                     const float* __restrict__ ob,
                                                     float* __restrict__ dy,
                                                     float* __restrict__ dx,
                                                     float* __restrict__ msk) {
    __shared__ __align__(16) unsigned short sA[32 * APITCH];
    int t = threadIdx.x;
    int lane = t & 63, wv = t >> 6;
    int gp0 = blockIdx.x * 32;          // 32 | W: one row, one b per block
    int wo0 = gp0 % W_;
    int tmp = gp0 / W_;
    int ho = tmp % H_;
    int b  = tmp / H_;

    // ---- im2col gather (zero-pad borders), lanes = 64 channels ----
    {
        const float* xb = xt + (size_t)b * HW_ * 64 + lane;
        for (int i = 0; i < 72; i++) {
            int task = i * 4 + wv;      // 0..287 = k*32 + p
            int p = task & 31, k = task >> 5;
            int y  = ho + (k / 3) - 1;
            int xw = wo0 + p + (k % 3) - 1;
            float v = 0.f;
            if (y >= 0 && y < H_ && xw >= 0 && xw < W_)
                v = xb[(size_t)(y * W_ + xw) * 64];
            sA[p * APITCH + k * 64 + lane] = f2bf(v);
        }
    }
    __syncthreads();

    // ---- GEMM: wave wv -> (mtile = wv&1 pixels, ntile = wv>>1 channels) ----
    int mtile = wv & 1, ntile = wv >> 1;
    int m = lane & 15, q = lane >> 4;
    int oc = ntile * 16 + m;
    float bv = (oc < 27) ? ob[oc] : 0.f;
    f32x4 acc = {bv, bv, bv, bv};
    const unsigned short* arow = sA + (mtile * 16 + m) * APITCH + q * 8;
    const unsigned short* brow = wB2 + oc * KTOT + q * 8;
#pragma unroll
    for (int kk = 0; kk < 18; kk++) {
        bf16x8 af = *(const bf16x8*)(arow + kk * 32);
        bf16x8 bf = *(const bf16x8*)(brow + kk * 32);
        acc = __builtin_amdgcn_mfma_f32_16x16x32_bf16(af, bf, acc, 0, 0, 0);
    }

    // ---- direct store: 4 consecutive pixels (reg) x 1 channel per lane ----
    if (oc < 27) {
        int pbase = mtile * 16 + q * 4;           // pixel = pbase + reg
        if (oc < 18) {
            int k = oc >> 1;
            float* dst = (oc & 1) ? dx : dy;
            size_t addr = (size_t)(b * KK_ + k) * HW_ + (size_t)ho * W_ + wo0 + pbase;
            float4 r; r.x = acc[0]; r.y = acc[1]; r.z = acc[2]; r.w = acc[3];
            *(float4*)(dst + addr) = r;
        } else {
            int k = oc - 18;
            size_t addr = (size_t)(b * KK_ + k) * HW_ + (size_t)ho * W_ + wo0 + pbase;
            float4 r;
            r.x = 1.f / (1.f + expf(-acc[0]));
            r.y = 1.f / (1.f + expf(-acc[1]));
            r.z = 1.f / (1.f + expf(-acc[2]));
            r.w = 1.f / (1.f + expf(-acc[3]));
            *(float4*)(msk + addr) = r;
        }
    }
}

// ---------------------------------------------------------------------------
// Kernel 4: deformable conv via MFMA.
// Gather: R5/R6-verified fp32 bilinear arithmetic; only new op = f2bf on the
//   staged modulated sample.  LDS bf16 sA[32][584] (36.5 KB -> 4 blocks/CU).
// GEMM + direct store: R6-verified offset_mfma pattern, tile-for-tile
//   (wave -> mtile = wv&1, 2 n-tiles o0 = (wv>>1)*32 + m, o1 = o0+16).
// ---------------------------------------------------------------------------
__global__ __launch_bounds__(256, 4) void deform_mfma_k(const float* __restrict__ xt,
                                                        const float* __restrict__ dy_,
                                                        const float* __restrict__ dx_,
                                                        const float* __restrict__ msk_,
                                                        const unsigned short* __restrict__ wB,
                                                        const float* __restrict__ bias,
                                                        float* __restrict__ out) {
    __shared__ __align__(16) unsigned short sA[32 * APITCH];
    int t = threadIdx.x;
    int gp0 = blockIdx.x * 32;          // 32 | W, one row / one b per block
    int wo0 = gp0 % W_;
    int tmp = gp0 / W_;
    int ho = tmp % H_;
    int b = tmp / H_;

    // ---- gather phase (R5-exact fp32 arithmetic, f2bf at the end) ----
    {
        int c = t & 63;
        int wv = t >> 6;                // wave handles pixels wv*8..+7
        const float* xb = xt + (size_t)b * HW_ * 64 + c;
        for (int j = 0; j < 8; j++) {
            int p = wv * 8 + j;
            int wo = wo0 + p;
            int pixoff = (b * KK_) * HW_ + ho * W_ + wo;
            unsigned short* sp = sA + p * APITCH;
#pragma unroll
            for (int k = 0; k < 9; k++) {
                float dyv = dy_[pixoff + k * HW_];
                float dxv = dx_[pixoff + k * HW_];
                float mv  = msk_[pixoff + k * HW_];
                float py = dyv + (float)(k / 3) + (float)(ho - 1);
                float px = dxv + (float)(k % 3) + (float)(wo - 1);
                float y0f = floorf(py), x0f = floorf(px);
                float wy1 = py - y0f, wx1 = px - x0f;
                float wy0 = 1.f - wy1, wx0 = 1.f - wx1;
                int y0 = (int)y0f, x0 = (int)x0f;
                bool yv0 = (y0 >= 0) && (y0 < H_);
                bool yv1 = (y0 + 1 >= 0) && (y0 + 1 < H_);
                bool xv0 = (x0 >= 0) && (x0 < W_);
                bool xv1 = (x0 + 1 >= 0) && (x0 + 1 < W_);
                float v = 0.f;
                if (yv0 && xv0) v += wy0 * wx0 * xb[(size_t)(y0 * W_ + x0) * 64];
                if (yv0 && xv1) v += wy0 * wx1 * xb[(size_t)(y0 * W_ + x0 + 1) * 64];
                if (yv1 && xv0) v += wy1 * wx0 * xb[(size_t)((y0 + 1) * W_ + x0) * 64];
                if (yv1 && xv1) v += wy1 * wx1 * xb[(size_t)((y0 + 1) * W_ + x0 + 1) * 64];
                sp[k * 64 + c] = f2bf(v * mv);
            }
        }
    }
    __syncthreads();

    // ---- GEMM phase (R6-verified pattern; 2 n-tiles per wave) ----
    int lane = t & 63, wv = t >> 6;
    int mtile = wv & 1, npair = wv >> 1;
    int m = lane & 15, q = lane >> 4;
    int o0 = npair * 32 + m;
    int o1 = o0 + 16;
    float b0 = bias[o0], b1 = bias[o1];
    f32x4 acc0 = {b0, b0, b0, b0};
    f32x4 acc1 = {b1, b1, b1, b1};
    const unsigned short* arow = sA + (mtile * 16 + m) * APITCH + q * 8;
    const unsigned short* br0 = wB + o0 * KTOT + q * 8;
    const unsigned short* br1 = wB + o1 * KTOT + q * 8;
#pragma unroll
    for (int kk = 0; kk < 18; kk++) {
        bf16x8 af  = *(const bf16x8*)(arow + kk * 32);
        bf16x8 bf0 = *(const bf16x8*)(br0 + kk * 32);
        bf16x8 bf1 = *(const bf16x8*)(br1 + kk * 32);
        acc0 = __builtin_amdgcn_mfma_f32_16x16x32_bf16(af, bf0, acc0, 0, 0, 0);
        acc1 = __builtin_amdgcn_mfma_f32_16x16x32_bf16(af, bf1, acc1, 0, 0, 0);
    }

    // ---- direct store (R6-verified): pixel = mtile*16 + q*4 + reg ----
    int pbase = mtile * 16 + q * 4;
    size_t a0 = ((size_t)(b * COUT + o0)) * HW_ + (size_t)ho * W_ + wo0 + pbase;
    size_t a1 = ((size_t)(b * COUT + o1)) * HW_ + (size_t)ho * W_ + wo0 + pbase;
    float4 r0; r0.x = acc0[0]; r0.y = acc0[1]; r0.z = acc0[2]; r0.w = acc0[3];
    float4 r1; r1.x = acc1[0]; r1.y = acc1[1]; r1.z = acc1[2]; r1.w = acc1[3];
    *(float4*)(out + a0) = r0;
    *(float4*)(out + a1) = r1;
}

// ---------------------------------------------------------------------------
extern "C" void kernel_launch(void* const* d_in, const int* in_sizes, int n_in,
                              void* d_out, int out_size, void* d_ws, size_t ws_size,
                              hipStream_t stream) {
    const float* x    = (const float*)d_in[0];   // (4,64,160,160)
    const float* ow   = (const float*)d_in[1];   // (27,64,3,3)
    const float* ob   = (const float*)d_in[2];   // (27,)
    const float* wgt  = (const float*)d_in[3];   // (64,64,3,3)
    const float* bias = (const float*)d_in[4];   // (64,)
    float* out = (float*)d_out;                  // (4,64,160,160) fp32

    // workspace (floats): x_nhwc | dy | dx | mask | wB(bf16) | wB2(bf16)
    float* ws  = (float*)d_ws;
    float* xt  = ws;                                  // 6,553,600 f32
    float* dy  = xt + (size_t)B_ * HW_ * CIN;         // 921,600 f32 each
    float* dx  = dy + (size_t)B_ * KK_ * HW_;
    float* msk = dx + (size_t)B_ * KK_ * HW_;
    unsigned short* wB  = (unsigned short*)(msk + (size_t)B_ * KK_ * HW_);  // 36,864 u16
    unsigned short* wB2 = wB + (size_t)COUT * KTOT;                         // 18,432 u16

    transpose_x_k<<<B_ * H_ * 5, 256, 0, stream>>>(x, xt);
    prep_wB_k<<<(COUT * KTOT + 255) / 256, 256, 0, stream>>>(wgt, wB);
    prep_wB2_k<<<(32 * KTOT + 255) / 256, 256, 0, stream>>>(ow, wB2);
    offset_mfma_k<<<(B_ * HW_) / 32, 256, 0, stream>>>(xt, wB2, ob, dy, dx, msk);
    deform_mfma_k<<<(B_ * HW_) / 32, 256, 0, stream>>>(xt, dy, dx, msk, wB, bias, out);
}

// Round 8
// 395.605 us; speedup vs baseline: 3.5230x; 1.3737x over previous
//
#include <hip/hip_runtime.h>
#include <math.h>

#define B_ 4
#define CIN 64
#define H_ 160
#define W_ 160
#define COUT 64
#define KK_ 9
#define HW_ (H_ * W_)
#define KTOT 576      // 9 taps * 64 channels
#define APITCH 584    // bf16 LDS pitch: 1168 B = 73*16 (odd*16 -> b128 conflict-free)

typedef __attribute__((ext_vector_type(8))) short bf16x8;
typedef __attribute__((ext_vector_type(4))) float f32x4;

__device__ inline unsigned short f2bf(float f) {
    unsigned int u = __float_as_uint(f);
    u = (u + 0x7FFF + ((u >> 16) & 1)) >> 16;   // round-to-nearest-even
    return (unsigned short)u;
}

// ---------------------------------------------------------------------------
// Kernel 1: transpose x (NCHW fp32) -> xt NHWC fp32  [b][h][w][c]  (verified)
// ---------------------------------------------------------------------------
__global__ __launch_bounds__(256) void transpose_x_k(const float* __restrict__ x,
                                                     float* __restrict__ xt) {
    __shared__ float tile[64][33];
    int bid = blockIdx.x;             // b*H*5 + h*5 + wt
    int wt = bid % 5; int tmp = bid / 5;
    int h = tmp % H_; int b = tmp / H_;
    int wbase = wt * 32;
    int t = threadIdx.x;

    int w_r = t & 31, c_r = t >> 5;
    const float* xp = x + (size_t)b * CIN * HW_ + (size_t)h * W_ + wbase + w_r;
#pragma unroll
    for (int cl = 0; cl < 8; cl++) {
        int c = cl * 8 + c_r;
        tile[c][w_r] = xp[(size_t)c * HW_];
    }
    __syncthreads();

    int c_w = t & 63, w_w = t >> 6;
    float* op = xt + ((size_t)(b * H_ + h) * W_ + wbase) * 64 + c_w;
#pragma unroll
    for (int wl = 0; wl < 8; wl++) {
        int w = wl * 4 + w_w;
        op[(size_t)w * 64] = tile[c_w][w];
    }
}

// ---------------------------------------------------------------------------
// Kernel 2: main weight (Cout,Cin,3,3) fp32 -> wB bf16 [o][tap*64+c]
// ---------------------------------------------------------------------------
__global__ void prep_wB_k(const float* __restrict__ w, unsigned short* __restrict__ wB) {
    int i = blockIdx.x * 256 + threadIdx.x;     // 64*576
    if (i >= COUT * KTOT) return;
    int o = i / KTOT, r = i % KTOT;
    int tap = r >> 6, c = r & 63;
    wB[i] = f2bf(w[(o * CIN + c) * KK_ + tap]);
}

// ---------------------------------------------------------------------------
// Kernel 2b: offset weight (27,64,3,3) fp32 -> wB2 bf16 [n(32,pad0)][tap*64+c]
// ---------------------------------------------------------------------------
__global__ void prep_wB2_k(const float* __restrict__ w, unsigned short* __restrict__ wB2) {
    int i = blockIdx.x * 256 + threadIdx.x;     // 32*576
    if (i >= 32 * KTOT) return;
    int n = i / KTOT, r = i % KTOT;
    int tap = r >> 6, c = r & 63;
    wB2[i] = (n < 27) ? f2bf(w[(n * CIN + c) * KK_ + tap]) : (unsigned short)0;
}

// ---------------------------------------------------------------------------
// Kernel 3: offset conv via MFMA, M=16 pixel tile (R7-verified pattern,
// mtile bit dropped).  LDS 18.7 KB -> 8 blocks/CU.  Waves 0,1 do the two
// 16-oc n-tiles; all 4 waves gather.
// ---------------------------------------------------------------------------
__global__ __launch_bounds__(256, 8) void offset_mfma_k(const float* __restrict__ xt,
                                                        const unsigned short* __restrict__ wB2,
                                                        const float* __restrict__ ob,
                                                        float* __restrict__ dy,
                                                        float* __restrict__ dx,
                                                        float* __restrict__ msk) {
    __shared__ __align__(16) unsigned short sA[16 * APITCH];
    int t = threadIdx.x;
    int lane = t & 63, wv = t >> 6;
    int gp0 = blockIdx.x * 16;          // 16 | W: one row, one b per block
    int wo0 = gp0 % W_;
    int tmp = gp0 / W_;
    int ho = tmp % H_;
    int b  = tmp / H_;

    // ---- im2col gather (zero-pad borders), lanes = 64 channels ----
    {
        const float* xb = xt + (size_t)b * HW_ * 64 + lane;
        for (int i = 0; i < 36; i++) {
            int task = i * 4 + wv;      // 0..143 = k*16 + p
            int p = task & 15, k = task >> 4;
            int y  = ho + (k / 3) - 1;
            int xw = wo0 + p + (k % 3) - 1;
            float v = 0.f;
            if (y >= 0 && y < H_ && xw >= 0 && xw < W_)
                v = xb[(size_t)(y * W_ + xw) * 64];
            sA[p * APITCH + k * 64 + lane] = f2bf(v);
        }
    }
    __syncthreads();

    // ---- GEMM: waves 0,1 -> n-tile wv (oc = wv*16 + m) ----
    if (wv < 2) {
        int m = lane & 15, q = lane >> 4;
        int oc = wv * 16 + m;
        float bv = (oc < 27) ? ob[oc] : 0.f;
        f32x4 acc = {bv, bv, bv, bv};
        const unsigned short* arow = sA + m * APITCH + q * 8;
        const unsigned short* brow = wB2 + oc * KTOT + q * 8;
#pragma unroll
        for (int kk = 0; kk < 18; kk++) {
            bf16x8 af = *(const bf16x8*)(arow + kk * 32);
            bf16x8 bf = *(const bf16x8*)(brow + kk * 32);
            acc = __builtin_amdgcn_mfma_f32_16x16x32_bf16(af, bf, acc, 0, 0, 0);
        }

        // ---- direct store: pixel = q*4 + reg ----
        if (oc < 27) {
            int pbase = q * 4;
            if (oc < 18) {
                int k = oc >> 1;
                float* dst = (oc & 1) ? dx : dy;
                size_t addr = (size_t)(b * KK_ + k) * HW_ + (size_t)ho * W_ + wo0 + pbase;
                float4 r; r.x = acc[0]; r.y = acc[1]; r.z = acc[2]; r.w = acc[3];
                *(float4*)(dst + addr) = r;
            } else {
                int k = oc - 18;
                size_t addr = (size_t)(b * KK_ + k) * HW_ + (size_t)ho * W_ + wo0 + pbase;
                float4 r;
                r.x = 1.f / (1.f + expf(-acc[0]));
                r.y = 1.f / (1.f + expf(-acc[1]));
                r.z = 1.f / (1.f + expf(-acc[2]));
                r.w = 1.f / (1.f + expf(-acc[3]));
                *(float4*)(msk + addr) = r;
            }
        }
    }
}

// ---------------------------------------------------------------------------
// Kernel 4: deformable conv via MFMA, M=16 pixel tile (R7-verified pattern,
// mtile bit dropped).  LDS 18.7 KB -> 8 blocks/CU (2x resident waves).
// Gather: wave wv handles pixels wv*4..+3, R7-exact arithmetic.
// GEMM: wave wv -> n-tile wv (o = wv*16 + m), 18 MFMA, direct store.
// ---------------------------------------------------------------------------
__global__ __launch_bounds__(256, 8) void deform_mfma_k(const float* __restrict__ xt,
                                                        const float* __restrict__ dy_,
                                                        const float* __restrict__ dx_,
                                                        const float* __restrict__ msk_,
                                                        const unsigned short* __restrict__ wB,
                                                        const float* __restrict__ bias,
                                                        float* __restrict__ out) {
    __shared__ __align__(16) unsigned short sA[16 * APITCH];
    int t = threadIdx.x;
    int gp0 = blockIdx.x * 16;          // 16 | W, one row / one b per block
    int wo0 = gp0 % W_;
    int tmp = gp0 / W_;
    int ho = tmp % H_;
    int b = tmp / H_;

    // ---- gather phase (R7-exact fp32 arithmetic, f2bf at the end) ----
    {
        int c = t & 63;
        int wv = t >> 6;                // wave handles pixels wv*4..+3
        const float* xb = xt + (size_t)b * HW_ * 64 + c;
        for (int j = 0; j < 4; j++) {
            int p = wv * 4 + j;
            int wo = wo0 + p;
            int pixoff = (b * KK_) * HW_ + ho * W_ + wo;
            unsigned short* sp = sA + p * APITCH;
#pragma unroll
            for (int k = 0; k < 9; k++) {
                float dyv = dy_[pixoff + k * HW_];
                float dxv = dx_[pixoff + k * HW_];
                float mv  = msk_[pixoff + k * HW_];
                float py = dyv + (float)(k / 3) + (float)(ho - 1);
                float px = dxv + (float)(k % 3) + (float)(wo - 1);
                float y0f = floorf(py), x0f = floorf(px);
                float wy1 = py - y0f, wx1 = px - x0f;
                float wy0 = 1.f - wy1, wx0 = 1.f - wx1;
                int y0 = (int)y0f, x0 = (int)x0f;
                bool yv0 = (y0 >= 0) && (y0 < H_);
                bool yv1 = (y0 + 1 >= 0) && (y0 + 1 < H_);
                bool xv0 = (x0 >= 0) && (x0 < W_);
                bool xv1 = (x0 + 1 >= 0) && (x0 + 1 < W_);
                float v = 0.f;
                if (yv0 && xv0) v += wy0 * wx0 * xb[(size_t)(y0 * W_ + x0) * 64];
                if (yv0 && xv1) v += wy0 * wx1 * xb[(size_t)(y0 * W_ + x0 + 1) * 64];
                if (yv1 && xv0) v += wy1 * wx0 * xb[(size_t)((y0 + 1) * W_ + x0) * 64];
                if (yv1 && xv1) v += wy1 * wx1 * xb[(size_t)((y0 + 1) * W_ + x0 + 1) * 64];
                sp[k * 64 + c] = f2bf(v * mv);
            }
        }
    }
    __syncthreads();

    // ---- GEMM phase (R7-verified pattern; wave wv -> n-tile wv) ----
    int lane = t & 63, wv = t >> 6;
    int m = lane & 15, q = lane >> 4;
    int o0 = wv * 16 + m;
    float b0 = bias[o0];
    f32x4 acc0 = {b0, b0, b0, b0};
    const unsigned short* arow = sA + m * APITCH + q * 8;
    const unsigned short* br0 = wB + o0 * KTOT + q * 8;
#pragma unroll
    for (int kk = 0; kk < 18; kk++) {
        bf16x8 af  = *(const bf16x8*)(arow + kk * 32);
        bf16x8 bf0 = *(const bf16x8*)(br0 + kk * 32);
        acc0 = __builtin_amdgcn_mfma_f32_16x16x32_bf16(af, bf0, acc0, 0, 0, 0);
    }

    // ---- direct store (R7-verified): pixel = q*4 + reg ----
    int pbase = q * 4;
    size_t a0 = ((size_t)(b * COUT + o0)) * HW_ + (size_t)ho * W_ + wo0 + pbase;
    float4 r0; r0.x = acc0[0]; r0.y = acc0[1]; r0.z = acc0[2]; r0.w = acc0[3];
    *(float4*)(out + a0) = r0;
}

// ---------------------------------------------------------------------------
extern "C" void kernel_launch(void* const* d_in, const int* in_sizes, int n_in,
                              void* d_out, int out_size, void* d_ws, size_t ws_size,
                              hipStream_t stream) {
    const float* x    = (const float*)d_in[0];   // (4,64,160,160)
    const float* ow   = (const float*)d_in[1];   // (27,64,3,3)
    const float* ob   = (const float*)d_in[2];   // (27,)
    const float* wgt  = (const float*)d_in[3];   // (64,64,3,3)
    const float* bias = (const float*)d_in[4];   // (64,)
    float* out = (float*)d_out;                  // (4,64,160,160) fp32

    // workspace (floats): x_nhwc | dy | dx | mask | wB(bf16) | wB2(bf16)
    float* ws  = (float*)d_ws;
    float* xt  = ws;                                  // 6,553,600 f32
    float* dy  = xt + (size_t)B_ * HW_ * CIN;         // 921,600 f32 each
    float* dx  = dy + (size_t)B_ * KK_ * HW_;
    float* msk = dx + (size_t)B_ * KK_ * HW_;
    unsigned short* wB  = (unsigned short*)(msk + (size_t)B_ * KK_ * HW_);  // 36,864 u16
    unsigned short* wB2 = wB + (size_t)COUT * KTOT;                         // 18,432 u16

    transpose_x_k<<<B_ * H_ * 5, 256, 0, stream>>>(x, xt);
    prep_wB_k<<<(COUT * KTOT + 255) / 256, 256, 0, stream>>>(wgt, wB);
    prep_wB2_k<<<(32 * KTOT + 255) / 256, 256, 0, stream>>>(ow, wB2);
    offset_mfma_k<<<(B_ * HW_) / 16, 256, 0, stream>>>(xt, wB2, ob, dy, dx, msk);
    deform_mfma_k<<<(B_ * HW_) / 16, 256, 0, stream>>>(xt, dy, dx, msk, wB, bias, out);
}

// Round 9
// 247.131 us; speedup vs baseline: 5.6395x; 1.6008x over previous
//
#include <hip/hip_runtime.h>
#include <math.h>

#define B_ 4
#define CIN 64
#define H_ 160
#define W_ 160
#define COUT 64
#define KK_ 9
#define HW_ (H_ * W_)
#define KTOT 576      // 9 taps * 64 channels
#define APITCH 584    // bf16 LDS pitch: 1168 B = 73*16 (odd*16 -> b128 conflict-free)
#define NTILE 6400    // (B*HW)/16
#define TPX   800     // tiles per XCD slice (NTILE/8)

typedef __attribute__((ext_vector_type(8))) short bf16x8;
typedef __attribute__((ext_vector_type(4))) float f32x4;

__device__ inline unsigned short f2bf(float f) {
    unsigned int u = __float_as_uint(f);
    u = (u + 0x7FFF + ((u >> 16) & 1)) >> 16;   // round-to-nearest-even
    return (unsigned short)u;
}

// ---------------------------------------------------------------------------
// Kernel 1: transpose x (NCHW fp32) -> xt NHWC fp32  [b][h][w][c]  (verified)
// ---------------------------------------------------------------------------
__global__ __launch_bounds__(256) void transpose_x_k(const float* __restrict__ x,
                                                     float* __restrict__ xt) {
    __shared__ float tile[64][33];
    int bid = blockIdx.x;             // b*H*5 + h*5 + wt
    int wt = bid % 5; int tmp = bid / 5;
    int h = tmp % H_; int b = tmp / H_;
    int wbase = wt * 32;
    int t = threadIdx.x;

    int w_r = t & 31, c_r = t >> 5;
    const float* xp = x + (size_t)b * CIN * HW_ + (size_t)h * W_ + wbase + w_r;
#pragma unroll
    for (int cl = 0; cl < 8; cl++) {
        int c = cl * 8 + c_r;
        tile[c][w_r] = xp[(size_t)c * HW_];
    }
    __syncthreads();

    int c_w = t & 63, w_w = t >> 6;
    float* op = xt + ((size_t)(b * H_ + h) * W_ + wbase) * 64 + c_w;
#pragma unroll
    for (int wl = 0; wl < 8; wl++) {
        int w = wl * 4 + w_w;
        op[(size_t)w * 64] = tile[c_w][w];
    }
}

// ---------------------------------------------------------------------------
// Kernel 2: main weight (Cout,Cin,3,3) fp32 -> wB bf16 [o][tap*64+c]
// ---------------------------------------------------------------------------
__global__ void prep_wB_k(const float* __restrict__ w, unsigned short* __restrict__ wB) {
    int i = blockIdx.x * 256 + threadIdx.x;     // 64*576
    if (i >= COUT * KTOT) return;
    int o = i / KTOT, r = i % KTOT;
    int tap = r >> 6, c = r & 63;
    wB[i] = f2bf(w[(o * CIN + c) * KK_ + tap]);
}

// ---------------------------------------------------------------------------
// Kernel 2b: offset weight (27,64,3,3) fp32 -> wB2 bf16 [n(32,pad0)][tap*64+c]
// ---------------------------------------------------------------------------
__global__ void prep_wB2_k(const float* __restrict__ w, unsigned short* __restrict__ wB2) {
    int i = blockIdx.x * 256 + threadIdx.x;     // 32*576
    if (i >= 32 * KTOT) return;
    int n = i / KTOT, r = i % KTOT;
    int tap = r >> 6, c = r & 63;
    wB2[i] = (n < 27) ? f2bf(w[(n * CIN + c) * KK_ + tap]) : (unsigned short)0;
}

// ---------------------------------------------------------------------------
// Kernel 3: offset conv via MFMA, M=16 (R8-verified), + XCD swizzle.
// ---------------------------------------------------------------------------
__global__ __launch_bounds__(256, 8) void offset_mfma_k(const float* __restrict__ xt,
                                                        const unsigned short* __restrict__ wB2,
                                                        const float* __restrict__ ob,
                                                        float* __restrict__ dy,
                                                        float* __restrict__ dx,
                                                        float* __restrict__ msk) {
    __shared__ __align__(16) unsigned short sA[16 * APITCH];
    int t = threadIdx.x;
    int lane = t & 63, wv = t >> 6;
    int bid = blockIdx.x;
    int tile = (bid & 7) * TPX + (bid >> 3);   // XCD-contiguous image slices
    int gp0 = tile * 16;                // 16 | W: one row, one b per block
    int wo0 = gp0 % W_;
    int tmp = gp0 / W_;
    int ho = tmp % H_;
    int b  = tmp / H_;

    // ---- im2col gather (zero-pad borders), lanes = 64 channels ----
    {
        const float* xb = xt + (size_t)b * HW_ * 64 + lane;
        for (int i = 0; i < 36; i++) {
            int task = i * 4 + wv;      // 0..143 = k*16 + p
            int p = task & 15, k = task >> 4;
            int y  = ho + (k / 3) - 1;
            int xw = wo0 + p + (k % 3) - 1;
            float v = 0.f;
            if (y >= 0 && y < H_ && xw >= 0 && xw < W_)
                v = xb[(size_t)(y * W_ + xw) * 64];
            sA[p * APITCH + k * 64 + lane] = f2bf(v);
        }
    }
    __syncthreads();

    // ---- GEMM: waves 0,1 -> n-tile wv (oc = wv*16 + m) ----
    if (wv < 2) {
        int m = lane & 15, q = lane >> 4;
        int oc = wv * 16 + m;
        float bv = (oc < 27) ? ob[oc] : 0.f;
        f32x4 acc = {bv, bv, bv, bv};
        const unsigned short* arow = sA + m * APITCH + q * 8;
        const unsigned short* brow = wB2 + oc * KTOT + q * 8;
#pragma unroll
        for (int kk = 0; kk < 18; kk++) {
            bf16x8 af = *(const bf16x8*)(arow + kk * 32);
            bf16x8 bf = *(const bf16x8*)(brow + kk * 32);
            acc = __builtin_amdgcn_mfma_f32_16x16x32_bf16(af, bf, acc, 0, 0, 0);
        }

        // ---- direct store: pixel = q*4 + reg ----
        if (oc < 27) {
            int pbase = q * 4;
            if (oc < 18) {
                int k = oc >> 1;
                float* dst = (oc & 1) ? dx : dy;
                size_t addr = (size_t)(b * KK_ + k) * HW_ + (size_t)ho * W_ + wo0 + pbase;
                float4 r; r.x = acc[0]; r.y = acc[1]; r.z = acc[2]; r.w = acc[3];
                *(float4*)(dst + addr) = r;
            } else {
                int k = oc - 18;
                size_t addr = (size_t)(b * KK_ + k) * HW_ + (size_t)ho * W_ + wo0 + pbase;
                float4 r;
                r.x = 1.f / (1.f + expf(-acc[0]));
                r.y = 1.f / (1.f + expf(-acc[1]));
                r.z = 1.f / (1.f + expf(-acc[2]));
                r.w = 1.f / (1.f + expf(-acc[3]));
                *(float4*)(msk + addr) = r;
            }
        }
    }
}

// ---------------------------------------------------------------------------
// Kernel 4: deformable conv via MFMA, M=16 (R8-verified GEMM/store) +
// phase-0 param precompute (breaks the 2-round-trip gather chain) +
// XCD swizzle.  LDS ~21.6 KB -> 7 blocks/CU.
// ---------------------------------------------------------------------------
__global__ __launch_bounds__(256, 7) void deform_mfma_k(const float* __restrict__ xt,
                                                        const float* __restrict__ dy_,
                                                        const float* __restrict__ dx_,
                                                        const float* __restrict__ msk_,
                                                        const unsigned short* __restrict__ wB,
                                                        const float* __restrict__ bias,
                                                        float* __restrict__ out) {
    __shared__ __align__(16) unsigned short sA[16 * APITCH];
    __shared__ __align__(16) float4 spar_w[144];
    __shared__ __align__(8)  int2   spar_c[144];
    int t = threadIdx.x;
    int bid = blockIdx.x;
    int tile = (bid & 7) * TPX + (bid >> 3);   // XCD-contiguous image slices
    int gp0 = tile * 16;                // 16 | W, one row / one b per block
    int wo0 = gp0 % W_;
    int tmp = gp0 / W_;
    int ho = tmp % H_;
    int b = tmp / H_;

    // ---- phase 0: bilinear params, one (p,k) task per thread ----
    if (t < 144) {
        int p = t & 15, k = t >> 4;
        size_t off = (size_t)(b * KK_ + k) * HW_ + (size_t)ho * W_ + wo0 + p;
        float dyv = dy_[off];
        float dxv = dx_[off];
        float mv  = msk_[off];
        float py = dyv + (float)(k / 3) + (float)(ho - 1);
        float px = dxv + (float)(k % 3) + (float)(wo0 + p - 1);
        float y0f = floorf(py), x0f = floorf(px);
        float wy1 = py - y0f, wx1 = px - x0f;
        float wy0 = 1.f - wy1, wx0 = 1.f - wx1;
        int y0 = (int)y0f, x0 = (int)x0f;
        bool yv0 = (y0 >= 0) && (y0 < H_);
        bool yv1 = (y0 + 1 >= 0) && (y0 + 1 < H_);
        bool xv0 = (x0 >= 0) && (x0 < W_);
        bool xv1 = (x0 + 1 >= 0) && (x0 + 1 < W_);
        float4 w4;
        w4.x = (yv0 && xv0) ? wy0 * wx0 * mv : 0.f;
        w4.y = (yv0 && xv1) ? wy0 * wx1 * mv : 0.f;
        w4.z = (yv1 && xv0) ? wy1 * wx0 * mv : 0.f;
        w4.w = (yv1 && xv1) ? wy1 * wx1 * mv : 0.f;
        spar_w[t] = w4;
        int2 c2; c2.x = y0; c2.y = x0;
        spar_c[t] = c2;
    }
    __syncthreads();

    // ---- gather: single round-trip per task, params broadcast from LDS ----
    {
        int c = t & 63;
        int wv = t >> 6;
        const float* xb = xt + (size_t)b * HW_ * 64 + c;
#pragma unroll 6
        for (int i = 0; i < 36; i++) {
            int task = i * 4 + wv;      // 0..143 = k*16 + p
            int p = task & 15, k = task >> 4;
            float4 w4 = spar_w[task];
            int2 c2 = spar_c[task];
            int yc0 = min(max(c2.x, 0), H_ - 1);
            int yc1 = min(max(c2.x + 1, 0), H_ - 1);
            int xc0 = min(max(c2.y, 0), W_ - 1);
            int xc1 = min(max(c2.y + 1, 0), W_ - 1);
            float v00 = xb[(size_t)(yc0 * W_ + xc0) * 64];
            float v01 = xb[(size_t)(yc0 * W_ + xc1) * 64];
            float v10 = xb[(size_t)(yc1 * W_ + xc0) * 64];
            float v11 = xb[(size_t)(yc1 * W_ + xc1) * 64];
            float v = v00 * w4.x + v01 * w4.y + v10 * w4.z + v11 * w4.w;
            sA[p * APITCH + k * 64 + c] = f2bf(v);
        }
    }
    __syncthreads();

    // ---- GEMM phase (R8-verified; wave wv -> n-tile wv) ----
    int lane = t & 63, wv = t >> 6;
    int m = lane & 15, q = lane >> 4;
    int o0 = wv * 16 + m;
    float b0 = bias[o0];
    f32x4 acc0 = {b0, b0, b0, b0};
    const unsigned short* arow = sA + m * APITCH + q * 8;
    const unsigned short* br0 = wB + o0 * KTOT + q * 8;
#pragma unroll
    for (int kk = 0; kk < 18; kk++) {
        bf16x8 af  = *(const bf16x8*)(arow + kk * 32);
        bf16x8 bf0 = *(const bf16x8*)(br0 + kk * 32);
        acc0 = __builtin_amdgcn_mfma_f32_16x16x32_bf16(af, bf0, acc0, 0, 0, 0);
    }

    // ---- direct store (R8-verified): pixel = q*4 + reg ----
    int pbase = q * 4;
    size_t a0 = ((size_t)(b * COUT + o0)) * HW_ + (size_t)ho * W_ + wo0 + pbase;
    float4 r0; r0.x = acc0[0]; r0.y = acc0[1]; r0.z = acc0[2]; r0.w = acc0[3];
    *(float4*)(out + a0) = r0;
}

// ---------------------------------------------------------------------------
extern "C" void kernel_launch(void* const* d_in, const int* in_sizes, int n_in,
                              void* d_out, int out_size, void* d_ws, size_t ws_size,
                              hipStream_t stream) {
    const float* x    = (const float*)d_in[0];   // (4,64,160,160)
    const float* ow   = (const float*)d_in[1];   // (27,64,3,3)
    const float* ob   = (const float*)d_in[2];   // (27,)
    const float* wgt  = (const float*)d_in[3];   // (64,64,3,3)
    const float* bias = (const float*)d_in[4];   // (64,)
    float* out = (float*)d_out;                  // (4,64,160,160) fp32

    // workspace (floats): x_nhwc | dy | dx | mask | wB(bf16) | wB2(bf16)
    float* ws  = (float*)d_ws;
    float* xt  = ws;                                  // 6,553,600 f32
    float* dy  = xt + (size_t)B_ * HW_ * CIN;         // 921,600 f32 each
    float* dx  = dy + (size_t)B_ * KK_ * HW_;
    float* msk = dx + (size_t)B_ * KK_ * HW_;
    unsigned short* wB  = (unsigned short*)(msk + (size_t)B_ * KK_ * HW_);  // 36,864 u16
    unsigned short* wB2 = wB + (size_t)COUT * KTOT;                         // 18,432 u16

    transpose_x_k<<<B_ * H_ * 5, 256, 0, stream>>>(x, xt);
    prep_wB_k<<<(COUT * KTOT + 255) / 256, 256, 0, stream>>>(wgt, wB);
    prep_wB2_k<<<(32 * KTOT + 255) / 256, 256, 0, stream>>>(ow, wB2);
    offset_mfma_k<<<NTILE, 256, 0, stream>>>(xt, wB2, ob, dy, dx, msk);
    deform_mfma_k<<<NTILE, 256, 0, stream>>>(xt, dy, dx, msk, wB, bias, out);
}

// Round 10
// 244.587 us; speedup vs baseline: 5.6982x; 1.0104x over previous
//
#include <hip/hip_runtime.h>
#include <math.h>

#define B_ 4
#define CIN 64
#define H_ 160
#define W_ 160
#define COUT 64
#define KK_ 9
#define HW_ (H_ * W_)
#define KTOT 576      // 9 taps * 64 channels
#define APITCH 584    // bf16 LDS pitch: 1168 B = 73*16 (odd*16 -> b128 conflict-free)
#define SLPITCH 17    // offset-logit LDS pitch (floats)
#define NTILE 6400    // (B*HW)/16
#define TPX   800     // tiles per XCD slice (NTILE/8)

typedef __attribute__((ext_vector_type(8))) short bf16x8;
typedef __attribute__((ext_vector_type(4))) float f32x4;

__device__ inline unsigned short f2bf(float f) {
    unsigned int u = __float_as_uint(f);
    u = (u + 0x7FFF + ((u >> 16) & 1)) >> 16;   // round-to-nearest-even
    return (unsigned short)u;
}

// ---------------------------------------------------------------------------
// Kernel 1: transpose x (NCHW fp32) -> xt NHWC fp32  [b][h][w][c]  (verified)
// ---------------------------------------------------------------------------
__global__ __launch_bounds__(256) void transpose_x_k(const float* __restrict__ x,
                                                     float* __restrict__ xt) {
    __shared__ float tile[64][33];
    int bid = blockIdx.x;             // b*H*5 + h*5 + wt
    int wt = bid % 5; int tmp = bid / 5;
    int h = tmp % H_; int b = tmp / H_;
    int wbase = wt * 32;
    int t = threadIdx.x;

    int w_r = t & 31, c_r = t >> 5;
    const float* xp = x + (size_t)b * CIN * HW_ + (size_t)h * W_ + wbase + w_r;
#pragma unroll
    for (int cl = 0; cl < 8; cl++) {
        int c = cl * 8 + c_r;
        tile[c][w_r] = xp[(size_t)c * HW_];
    }
    __syncthreads();

    int c_w = t & 63, w_w = t >> 6;
    float* op = xt + ((size_t)(b * H_ + h) * W_ + wbase) * 64 + c_w;
#pragma unroll
    for (int wl = 0; wl < 8; wl++) {
        int w = wl * 4 + w_w;
        op[(size_t)w * 64] = tile[c_w][w];
    }
}

// ---------------------------------------------------------------------------
// Kernel 2: main weight (Cout,Cin,3,3) fp32 -> wB bf16 [o][tap*64+c]
// ---------------------------------------------------------------------------
__global__ void prep_wB_k(const float* __restrict__ w, unsigned short* __restrict__ wB) {
    int i = blockIdx.x * 256 + threadIdx.x;     // 64*576
    if (i >= COUT * KTOT) return;
    int o = i / KTOT, r = i % KTOT;
    int tap = r >> 6, c = r & 63;
    wB[i] = f2bf(w[(o * CIN + c) * KK_ + tap]);
}

// ---------------------------------------------------------------------------
// Kernel 2b: offset weight (27,64,3,3) fp32 -> wB2 bf16 [n(32,pad0)][tap*64+c]
// ---------------------------------------------------------------------------
__global__ void prep_wB2_k(const float* __restrict__ w, unsigned short* __restrict__ wB2) {
    int i = blockIdx.x * 256 + threadIdx.x;     // 32*576
    if (i >= 32 * KTOT) return;
    int n = i / KTOT, r = i % KTOT;
    int tap = r >> 6, c = r & 63;
    wB2[i] = (n < 27) ? f2bf(w[(n * CIN + c) * KK_ + tap]) : (unsigned short)0;
}

// ---------------------------------------------------------------------------
// Kernel 3: FUSED DCNv2 per 16-pixel tile.
//  A: im2col x -> sA bf16 (verified R8/R9 pattern)
//  B: offset GEMM, waves 0,1 (verified GEMM; D-store -> LDS slog, sigmoid
//     folded for mask rows, bias in acc init)
//  C: bilinear params from slog (verified R9 phase-0; corner offsets
//     precomputed as int4 element offsets)
//  D: gather -> sA overwrite (verified R9, clamps hoisted to C)
//  E: main GEMM + direct store (verified R9)
// ---------------------------------------------------------------------------
__global__ __launch_bounds__(256, 6) void fused_dcn_k(const float* __restrict__ xt,
                                                      const unsigned short* __restrict__ wB2,
                                                      const float* __restrict__ ob,
                                                      const unsigned short* __restrict__ wB,
                                                      const float* __restrict__ bias,
                                                      float* __restrict__ out) {
    __shared__ __align__(16) unsigned short sA[16 * APITCH];   // 18.7 KB
    __shared__ float slog[27 * SLPITCH];                       // 1.8 KB
    __shared__ __align__(16) float4 spar_w[144];               // 2.3 KB
    __shared__ __align__(16) int4   spar_o[144];               // 2.3 KB
    int t = threadIdx.x;
    int lane = t & 63, wv = t >> 6;
    int bid = blockIdx.x;
    int tile = (bid & 7) * TPX + (bid >> 3);   // XCD-contiguous image slices
    int gp0 = tile * 16;                // 16 | W: one row, one b per block
    int wo0 = gp0 % W_;
    int tmp = gp0 / W_;
    int ho = tmp % H_;
    int b  = tmp / H_;

    const float* xb = xt + (size_t)b * HW_ * 64 + lane;

    // ---- phase A: im2col gather (zero-pad borders), lanes = 64 channels ----
    for (int i = 0; i < 36; i++) {
        int task = i * 4 + wv;          // 0..143 = k*16 + p
        int p = task & 15, k = task >> 4;
        int y  = ho + (k / 3) - 1;
        int xw = wo0 + p + (k % 3) - 1;
        float v = 0.f;
        if (y >= 0 && y < H_ && xw >= 0 && xw < W_)
            v = xb[(size_t)(y * W_ + xw) * 64];
        sA[p * APITCH + k * 64 + lane] = f2bf(v);
    }
    __syncthreads();

    // ---- phase B: offset GEMM (waves 0,1), D-store -> slog ----
    if (wv < 2) {
        int m = lane & 15, q = lane >> 4;
        int oc = wv * 16 + m;
        float bv = (oc < 27) ? ob[oc] : 0.f;
        f32x4 acc = {bv, bv, bv, bv};
        const unsigned short* arow = sA + m * APITCH + q * 8;
        const unsigned short* brow = wB2 + oc * KTOT + q * 8;
#pragma unroll
        for (int kk = 0; kk < 18; kk++) {
            bf16x8 af = *(const bf16x8*)(arow + kk * 32);
            bf16x8 bf = *(const bf16x8*)(brow + kk * 32);
            acc = __builtin_amdgcn_mfma_f32_16x16x32_bf16(af, bf, acc, 0, 0, 0);
        }
        if (oc < 27) {
            float* sl = slog + oc * SLPITCH + q * 4;   // pixel = q*4 + reg
            if (oc < 18) {
#pragma unroll
                for (int r = 0; r < 4; r++) sl[r] = acc[r];
            } else {
#pragma unroll
                for (int r = 0; r < 4; r++) sl[r] = 1.f / (1.f + expf(-acc[r]));
            }
        }
    }
    __syncthreads();

    // ---- phase C: bilinear params, one (p,k) task per thread ----
    if (t < 144) {
        int p = t & 15, k = t >> 4;
        float dyv = slog[(2 * k) * SLPITCH + p];
        float dxv = slog[(2 * k + 1) * SLPITCH + p];
        float mv  = slog[(18 + k) * SLPITCH + p];
        float py = dyv + (float)(k / 3) + (float)(ho - 1);
        float px = dxv + (float)(k % 3) + (float)(wo0 + p - 1);
        float y0f = floorf(py), x0f = floorf(px);
        float wy1 = py - y0f, wx1 = px - x0f;
        float wy0 = 1.f - wy1, wx0 = 1.f - wx1;
        int y0 = (int)y0f, x0 = (int)x0f;
        bool yv0 = (y0 >= 0) && (y0 < H_);
        bool yv1 = (y0 + 1 >= 0) && (y0 + 1 < H_);
        bool xv0 = (x0 >= 0) && (x0 < W_);
        bool xv1 = (x0 + 1 >= 0) && (x0 + 1 < W_);
        float4 w4;
        w4.x = (yv0 && xv0) ? wy0 * wx0 * mv : 0.f;
        w4.y = (yv0 && xv1) ? wy0 * wx1 * mv : 0.f;
        w4.z = (yv1 && xv0) ? wy1 * wx0 * mv : 0.f;
        w4.w = (yv1 && xv1) ? wy1 * wx1 * mv : 0.f;
        spar_w[t] = w4;
        int yc0 = min(max(y0, 0), H_ - 1), yc1 = min(max(y0 + 1, 0), H_ - 1);
        int xc0 = min(max(x0, 0), W_ - 1), xc1 = min(max(x0 + 1, 0), W_ - 1);
        int4 o4;
        o4.x = (yc0 * W_ + xc0) * 64;
        o4.y = (yc0 * W_ + xc1) * 64;
        o4.z = (yc1 * W_ + xc0) * 64;
        o4.w = (yc1 * W_ + xc1) * 64;
        spar_o[t] = o4;
    }
    __syncthreads();

    // ---- phase D: gather, single round-trip per task, params from LDS ----
#pragma unroll 6
    for (int i = 0; i < 36; i++) {
        int task = i * 4 + wv;          // 0..143 = k*16 + p
        int p = task & 15, k = task >> 4;
        float4 w4 = spar_w[task];
        int4  o4 = spar_o[task];
        float v00 = xb[o4.x];
        float v01 = xb[o4.y];
        float v10 = xb[o4.z];
        float v11 = xb[o4.w];
        float v = v00 * w4.x + v01 * w4.y + v10 * w4.z + v11 * w4.w;
        sA[p * APITCH + k * 64 + lane] = f2bf(v);
    }
    __syncthreads();

    // ---- phase E: main GEMM (verified; wave wv -> n-tile wv) ----
    int m = lane & 15, q = lane >> 4;
    int o0 = wv * 16 + m;
    float b0 = bias[o0];
    f32x4 acc0 = {b0, b0, b0, b0};
    const unsigned short* arow = sA + m * APITCH + q * 8;
    const unsigned short* br0 = wB + o0 * KTOT + q * 8;
#pragma unroll
    for (int kk = 0; kk < 18; kk++) {
        bf16x8 af  = *(const bf16x8*)(arow + kk * 32);
        bf16x8 bf0 = *(const bf16x8*)(br0 + kk * 32);
        acc0 = __builtin_amdgcn_mfma_f32_16x16x32_bf16(af, bf0, acc0, 0, 0, 0);
    }

    // ---- direct store (verified): pixel = q*4 + reg ----
    size_t a0 = ((size_t)(b * COUT + o0)) * HW_ + (size_t)ho * W_ + wo0 + q * 4;
    float4 r0; r0.x = acc0[0]; r0.y = acc0[1]; r0.z = acc0[2]; r0.w = acc0[3];
    *(float4*)(out + a0) = r0;
}

// ---------------------------------------------------------------------------
extern "C" void kernel_launch(void* const* d_in, const int* in_sizes, int n_in,
                              void* d_out, int out_size, void* d_ws, size_t ws_size,
                              hipStream_t stream) {
    const float* x    = (const float*)d_in[0];   // (4,64,160,160)
    const float* ow   = (const float*)d_in[1];   // (27,64,3,3)
    const float* ob   = (const float*)d_in[2];   // (27,)
    const float* wgt  = (const float*)d_in[3];   // (64,64,3,3)
    const float* bias = (const float*)d_in[4];   // (64,)
    float* out = (float*)d_out;                  // (4,64,160,160) fp32

    // workspace: xt fp32 NHWC | wB bf16 | wB2 bf16   (~26.3 MB)
    float* ws  = (float*)d_ws;
    float* xt  = ws;                                            // 6,553,600 f32
    unsigned short* wB  = (unsigned short*)(xt + (size_t)B_ * HW_ * CIN);  // 36,864 u16
    unsigned short* wB2 = wB + (size_t)COUT * KTOT;                        // 18,432 u16

    transpose_x_k<<<B_ * H_ * 5, 256, 0, stream>>>(x, xt);
    prep_wB_k<<<(COUT * KTOT + 255) / 256, 256, 0, stream>>>(wgt, wB);
    prep_wB2_k<<<(32 * KTOT + 255) / 256, 256, 0, stream>>>(ow, wB2);
    fused_dcn_k<<<NTILE, 256, 0, stream>>>(xt, wB2, ob, wB, bias, out);
}

// Round 11
// 202.591 us; speedup vs baseline: 6.8794x; 1.2073x over previous
//
#include <hip/hip_runtime.h>
#include <math.h>

#define B_ 4
#define CIN 64
#define H_ 160
#define W_ 160
#define COUT 64
#define KK_ 9
#define HW_ (H_ * W_)
#define KTOT 576      // 9 taps * 64 channels
#define APITCH 584    // bf16 LDS pitch: 1168 B = 73*16 (odd*16 -> b128 conflict-free)
#define XPITCH 72     // strip pitch (u16): 144 B = 9*16, b128-aligned, bank-rotating
#define SLPITCH 17    // offset-logit LDS pitch (floats)
#define NTILE 6400    // (B*HW)/16
#define TPX   800     // tiles per XCD slice (NTILE/8)

typedef __attribute__((ext_vector_type(8))) short bf16x8;
typedef __attribute__((ext_vector_type(4))) float f32x4;

__device__ inline unsigned short f2bf(float f) {
    unsigned int u = __float_as_uint(f);
    u = (u + 0x7FFF + ((u >> 16) & 1)) >> 16;   // round-to-nearest-even
    return (unsigned short)u;
}

// ---------------------------------------------------------------------------
// Kernel 1 (merged prep): grid-split into
//   [0, 3200)        : transpose x (NCHW fp32) -> xt NHWC fp32 (verified)
//   [3200, 3344)     : main weight -> wB bf16 [o][tap*64+c]
//   [3344, 3416)     : offset weight -> wB2 bf16 [n(32,pad0)][tap*64+c]
// ---------------------------------------------------------------------------
__global__ __launch_bounds__(256) void prep_all_k(const float* __restrict__ x,
                                                  const float* __restrict__ wgt,
                                                  const float* __restrict__ ow,
                                                  float* __restrict__ xt,
                                                  unsigned short* __restrict__ wB,
                                                  unsigned short* __restrict__ wB2) {
    __shared__ float tile[64][33];
    int bid = blockIdx.x;
    int t = threadIdx.x;

    if (bid < 3200) {
        int wt = bid % 5; int tmp = bid / 5;
        int h = tmp % H_; int b = tmp / H_;
        int wbase = wt * 32;

        int w_r = t & 31, c_r = t >> 5;
        const float* xp = x + (size_t)b * CIN * HW_ + (size_t)h * W_ + wbase + w_r;
#pragma unroll
        for (int cl = 0; cl < 8; cl++) {
            int c = cl * 8 + c_r;
            tile[c][w_r] = xp[(size_t)c * HW_];
        }
        __syncthreads();

        int c_w = t & 63, w_w = t >> 6;
        float* op = xt + ((size_t)(b * H_ + h) * W_ + wbase) * 64 + c_w;
#pragma unroll
        for (int wl = 0; wl < 8; wl++) {
            int w = wl * 4 + w_w;
            op[(size_t)w * 64] = tile[c_w][w];
        }
    } else if (bid < 3344) {
        int i = (bid - 3200) * 256 + t;          // 64*576 = 36864
        int o = i / KTOT, r = i % KTOT;
        int tap = r >> 6, c = r & 63;
        wB[i] = f2bf(wgt[(o * CIN + c) * KK_ + tap]);
    } else {
        int i = (bid - 3344) * 256 + t;          // 32*576 = 18432
        int n = i / KTOT, r = i % KTOT;
        int tap = r >> 6, c = r & 63;
        wB2[i] = (n < 27) ? f2bf(ow[(n * CIN + c) * KK_ + tap]) : (unsigned short)0;
    }
}

// ---------------------------------------------------------------------------
// Kernel 2: FUSED DCNv2 per 16-pixel tile.
//  A: load 3x18 distinct-pixel strip -> sX bf16 (54 rows; values bit-identical
//     to the old 144-row im2col, just deduplicated)
//  B: offset GEMM, waves 0,1 (verified GEMM; A-fragment row remapped to
//     (tap/3)*18 + tap%3 + m in sX; D-store -> slog with sigmoid folded)
//  C: bilinear params from slog (verified; corner element-offsets as int4)
//  D: gather -> sA (overlays sX; verified math, 4-task batched loads)
//  E: main GEMM + direct store (verified)
// ---------------------------------------------------------------------------
__global__ __launch_bounds__(256, 6) void fused_dcn_k(const float* __restrict__ xt,
                                                      const unsigned short* __restrict__ wB2,
                                                      const float* __restrict__ ob,
                                                      const unsigned short* __restrict__ wB,
                                                      const float* __restrict__ bias,
                                                      float* __restrict__ out) {
    __shared__ __align__(16) char ubuf[16 * APITCH * 2];   // sX (A/B) -> sA (D/E), 18.7 KB
    __shared__ __align__(16) char pbuf[144 * 32];          // spar_w | spar_o, 4.6 KB
    __shared__ float slog[27 * SLPITCH];                   // 1.8 KB
    unsigned short* sX = (unsigned short*)ubuf;            // 54 x XPITCH
    unsigned short* sA = (unsigned short*)ubuf;            // 16 x APITCH
    float4* spar_w = (float4*)pbuf;
    int4*   spar_o = (int4*)(pbuf + 144 * 16);

    int t = threadIdx.x;
    int lane = t & 63, wv = t >> 6;
    int bid = blockIdx.x;
    int tile = (bid & 7) * TPX + (bid >> 3);   // XCD-contiguous image slices
    int gp0 = tile * 16;                // 16 | W: one row, one b per block
    int wo0 = gp0 % W_;
    int tmp = gp0 / W_;
    int ho = tmp % H_;
    int b  = tmp / H_;

    const float* xb = xt + (size_t)b * HW_ * 64 + lane;

    // ---- phase A: 54-row strip load (zero-pad OOB), lanes = 64 channels ----
    for (int i = 0; i < 14; i++) {
        int r = i * 4 + wv;             // 0..55
        if (r < 54) {
            int yy = ho - 1 + r / 18;
            int xx = wo0 - 1 + r % 18;
            float v = 0.f;
            if (yy >= 0 && yy < H_ && xx >= 0 && xx < W_)
                v = xb[(size_t)(yy * W_ + xx) * 64];
            sX[r * XPITCH + lane] = f2bf(v);
        }
    }
    __syncthreads();

    // ---- phase B: offset GEMM (waves 0,1), A-frag from sX, D -> slog ----
    if (wv < 2) {
        int m = lane & 15, q = lane >> 4;
        int oc = wv * 16 + m;
        float bv = (oc < 27) ? ob[oc] : 0.f;
        f32x4 acc = {bv, bv, bv, bv};
        const unsigned short* brow = wB2 + oc * KTOT + q * 8;
#pragma unroll
        for (int kk = 0; kk < 18; kk++) {
            int tap = kk >> 1;
            int row = (tap / 3) * 18 + (tap % 3) + m;       // strip row for (m, tap)
            bf16x8 af = *(const bf16x8*)(sX + row * XPITCH + (kk & 1) * 32 + q * 8);
            bf16x8 bf = *(const bf16x8*)(brow + kk * 32);
            acc = __builtin_amdgcn_mfma_f32_16x16x32_bf16(af, bf, acc, 0, 0, 0);
        }
        if (oc < 27) {
            float* sl = slog + oc * SLPITCH + q * 4;        // pixel = q*4 + reg
            if (oc < 18) {
#pragma unroll
                for (int r = 0; r < 4; r++) sl[r] = acc[r];
            } else {
#pragma unroll
                for (int r = 0; r < 4; r++) sl[r] = 1.f / (1.f + expf(-acc[r]));
            }
        }
    }
    __syncthreads();

    // ---- phase C: bilinear params, one (p,k) task per thread ----
    if (t < 144) {
        int p = t & 15, k = t >> 4;
        float dyv = slog[(2 * k) * SLPITCH + p];
        float dxv = slog[(2 * k + 1) * SLPITCH + p];
        float mv  = slog[(18 + k) * SLPITCH + p];
        float py = dyv + (float)(k / 3) + (float)(ho - 1);
        float px = dxv + (float)(k % 3) + (float)(wo0 + p - 1);
        float y0f = floorf(py), x0f = floorf(px);
        float wy1 = py - y0f, wx1 = px - x0f;
        float wy0 = 1.f - wy1, wx0 = 1.f - wx1;
        int y0 = (int)y0f, x0 = (int)x0f;
        bool yv0 = (y0 >= 0) && (y0 < H_);
        bool yv1 = (y0 + 1 >= 0) && (y0 + 1 < H_);
        bool xv0 = (x0 >= 0) && (x0 < W_);
        bool xv1 = (x0 + 1 >= 0) && (x0 + 1 < W_);
        float4 w4;
        w4.x = (yv0 && xv0) ? wy0 * wx0 * mv : 0.f;
        w4.y = (yv0 && xv1) ? wy0 * wx1 * mv : 0.f;
        w4.z = (yv1 && xv0) ? wy1 * wx0 * mv : 0.f;
        w4.w = (yv1 && xv1) ? wy1 * wx1 * mv : 0.f;
        spar_w[t] = w4;
        int yc0 = min(max(y0, 0), H_ - 1), yc1 = min(max(y0 + 1, 0), H_ - 1);
        int xc0 = min(max(x0, 0), W_ - 1), xc1 = min(max(x0 + 1, 0), W_ - 1);
        int4 o4;
        o4.x = (yc0 * W_ + xc0) * 64;
        o4.y = (yc0 * W_ + xc1) * 64;
        o4.z = (yc1 * W_ + xc0) * 64;
        o4.w = (yc1 * W_ + xc1) * 64;
        spar_o[t] = o4;
    }
    __syncthreads();

    // ---- phase D: gather -> sA (overlays sX), 4-task batched loads ----
#pragma unroll
    for (int g = 0; g < 9; g++) {
        float4 w4[4]; int4 o4[4];
        float v00[4], v01[4], v10[4], v11[4];
#pragma unroll
        for (int j = 0; j < 4; j++) {
            int task = (g * 4 + j) * 4 + wv;
            w4[j] = spar_w[task];
            o4[j] = spar_o[task];
        }
#pragma unroll
        for (int j = 0; j < 4; j++) {
            v00[j] = xb[o4[j].x];
            v01[j] = xb[o4[j].y];
            v10[j] = xb[o4[j].z];
            v11[j] = xb[o4[j].w];
        }
#pragma unroll
        for (int j = 0; j < 4; j++) {
            int task = (g * 4 + j) * 4 + wv;
            int p = task & 15, k = task >> 4;
            float v = v00[j] * w4[j].x + v01[j] * w4[j].y
                    + v10[j] * w4[j].z + v11[j] * w4[j].w;
            sA[p * APITCH + k * 64 + lane] = f2bf(v);
        }
    }
    __syncthreads();

    // ---- phase E: main GEMM (verified; wave wv -> n-tile wv) ----
    int m = lane & 15, q = lane >> 4;
    int o0 = wv * 16 + m;
    float b0 = bias[o0];
    f32x4 acc0 = {b0, b0, b0, b0};
    const unsigned short* arow = sA + m * APITCH + q * 8;
    const unsigned short* br0 = wB + o0 * KTOT + q * 8;
#pragma unroll
    for (int kk = 0; kk < 18; kk++) {
        bf16x8 af  = *(const bf16x8*)(arow + kk * 32);
        bf16x8 bf0 = *(const bf16x8*)(br0 + kk * 32);
        acc0 = __builtin_amdgcn_mfma_f32_16x16x32_bf16(af, bf0, acc0, 0, 0, 0);
    }

    // ---- direct store (verified): pixel = q*4 + reg ----
    size_t a0 = ((size_t)(b * COUT + o0)) * HW_ + (size_t)ho * W_ + wo0 + q * 4;
    float4 r0; r0.x = acc0[0]; r0.y = acc0[1]; r0.z = acc0[2]; r0.w = acc0[3];
    *(float4*)(out + a0) = r0;
}

// ---------------------------------------------------------------------------
extern "C" void kernel_launch(void* const* d_in, const int* in_sizes, int n_in,
                              void* d_out, int out_size, void* d_ws, size_t ws_size,
                              hipStream_t stream) {
    const float* x    = (const float*)d_in[0];   // (4,64,160,160)
    const float* ow   = (const float*)d_in[1];   // (27,64,3,3)
    const float* ob   = (const float*)d_in[2];   // (27,)
    const float* wgt  = (const float*)d_in[3];   // (64,64,3,3)
    const float* bias = (const float*)d_in[4];   // (64,)
    float* out = (float*)d_out;                  // (4,64,160,160) fp32

    // workspace: xt fp32 NHWC | wB bf16 | wB2 bf16   (~26.3 MB)
    float* ws  = (float*)d_ws;
    float* xt  = ws;                                            // 6,553,600 f32
    unsigned short* wB  = (unsigned short*)(xt + (size_t)B_ * HW_ * CIN);  // 36,864 u16
    unsigned short* wB2 = wB + (size_t)COUT * KTOT;                        // 18,432 u16

    prep_all_k<<<3416, 256, 0, stream>>>(x, wgt, ow, xt, wB, wB2);
    fused_dcn_k<<<NTILE, 256, 0, stream>>>(xt, wB2, ob, wB, bias, out);
}